// Round 1
// baseline (1998.380 us; speedup 1.0000x reference)
//
#include <hip/hip_runtime.h>
#include <hip/hip_bf16.h>

// ---------------------------------------------------------------------------
// Problem constants (from reference)
// ---------------------------------------------------------------------------
#define B_GRAPHS 64
#define LMAX 1024
#define NP_TOT 49152      // sum(LENS)
#define NC_TOT 2560       // 64*40
#define EP_TOT 393216     // 8 * NP
#define EC_TOT 10240      // 4 * NC

__device__ __forceinline__ float lrelu(float x) { return x > 0.f ? x : 0.01f * x; }

// ---------------------------------------------------------------------------
// small utility kernels
// ---------------------------------------------------------------------------
__global__ void zero_int_kernel(int* p, int n) {
    int i = blockIdx.x * blockDim.x + threadIdx.x;
    if (i < n) p[i] = 0;
}

__global__ void hist_kernel(const int* __restrict__ tgt, int* __restrict__ deg, int E) {
    int e = blockIdx.x * blockDim.x + threadIdx.x;
    if (e < E) atomicAdd(&deg[tgt[e]], 1);
}

// single-block exclusive scan; out has n+1 entries (out[n] = total)
__global__ void exscan_kernel(const int* __restrict__ in, int* __restrict__ out, int n) {
    __shared__ int part[256];
    int t = threadIdx.x;
    int chunk = (n + 255) / 256;
    int lo = t * chunk;
    int hi = lo + chunk; if (hi > n) hi = n;
    int s = 0;
    for (int i = lo; i < hi; i++) s += in[i];
    part[t] = s;
    __syncthreads();
    if (t == 0) {
        int run = 0;
        for (int i = 0; i < 256; i++) { int v = part[i]; part[i] = run; run += v; }
    }
    __syncthreads();
    int run = part[t];
    for (int i = lo; i < hi; i++) { out[i] = run; run += in[i]; }
    if (t == 255) out[n] = run;
}

__global__ void scatter_kernel(const int* __restrict__ src, const int* __restrict__ tgt,
                               const int* __restrict__ rowptr, int* __restrict__ cursor,
                               int* __restrict__ csr, int E) {
    int e = blockIdx.x * blockDim.x + threadIdx.x;
    if (e >= E) return;
    int t = tgt[e];
    int pos = atomicAdd(&cursor[t], 1);
    csr[rowptr[t] + pos] = src[e];
}

// ---------------------------------------------------------------------------
// conv1d over packed rows: out[i, o] = b[o] + sum_{c,k} seq[b, l+k-2, c] * w[o,c,k]
// ---------------------------------------------------------------------------
#define CONV_ROWS 16
__global__ __launch_bounds__(128) void conv1d_packed_kernel(
    const float* __restrict__ seq, const float* __restrict__ w,
    const float* __restrict__ bvec, const int* __restrict__ gather,
    float* __restrict__ out, int np)
{
    __shared__ float ws[128 * 105];
    __shared__ float xs[5 * 21];
    int t = threadIdx.x;   // 128 = output channel
    for (int i = t; i < 128 * 105; i += 128) ws[i] = w[i];
    float bias = bvec[t];
    int row0 = blockIdx.x * CONV_ROWS;
    const float* wo = ws + t * 105;   // [c*5 + k]
    for (int r = 0; r < CONV_ROWS; r++) {
        int i = row0 + r;
        if (i >= np) break;
        int g = gather[i];
        int bb = g >> 10;
        int l = g & (LMAX - 1);
        __syncthreads();
        for (int j = t; j < 105; j += 128) {
            int k = j / 21, c = j % 21;
            int ll = l + k - 2;
            xs[j] = (ll >= 0 && ll < LMAX) ? seq[((long)bb * LMAX + ll) * 21 + c] : 0.f;
        }
        __syncthreads();
        float acc = bias;
        #pragma unroll
        for (int c = 0; c < 21; c++)
            #pragma unroll
            for (int k = 0; k < 5; k++)
                acc += xs[k * 21 + c] * wo[c * 5 + k];
        out[(long)i * 128 + t] = acc;
    }
}

// ---------------------------------------------------------------------------
// CSR aggregation: agg[i] = sum_{j in csr[rowptr[i]..rowptr[i+1])} x[j]
// one wave (64 lanes) per node; D <= 256
// ---------------------------------------------------------------------------
__global__ __launch_bounds__(256) void sage_agg_kernel(
    const float* __restrict__ x, const int* __restrict__ rowptr,
    const int* __restrict__ csr, float* __restrict__ agg, int n, int D)
{
    int wave = (blockIdx.x * blockDim.x + threadIdx.x) >> 6;
    int lane = threadIdx.x & 63;
    if (wave >= n) return;
    int beg = rowptr[wave], end = rowptr[wave + 1];
    float acc[4] = {0.f, 0.f, 0.f, 0.f};
    for (int j = beg; j < end; j++) {
        int s = csr[j];
        const float* xr = x + (long)s * D;
        int q = 0;
        for (int d = lane; d < D; d += 64, q++) acc[q] += xr[d];
    }
    float* ar = agg + (long)wave * D;
    int q = 0;
    for (int d = lane; d < D; d += 64, q++) ar[d] = acc[q];
}

// ---------------------------------------------------------------------------
// fused dual GEMM: Out = lrelu(A0 @ W0 + A1 @ W1 + bias)
// A0,A1: [N,K]; W0,W1: [K,Dout]; N % 64 == 0, Dout % 64 == 0; K arbitrary
// ---------------------------------------------------------------------------
__global__ __launch_bounds__(256) void sage_gemm_kernel(
    const float* __restrict__ A0, const float* __restrict__ W0,
    const float* __restrict__ A1, const float* __restrict__ W1,
    const float* __restrict__ bias, float* __restrict__ Out,
    int N, int K, int Dout)
{
    const int BM = 64, BN = 64, BK = 16;
    __shared__ float As[BK][BM];
    __shared__ float Bs[BK][BN];
    int tid = threadIdx.x;
    int r0 = blockIdx.x * BM;
    int c0 = blockIdx.y * BN;
    int tm = tid >> 4, tn = tid & 15;
    float acc[4][4] = {};

    for (int pass = 0; pass < 2; pass++) {
        const float* A = pass ? A1 : A0;
        const float* W = pass ? W1 : W0;
        for (int k0 = 0; k0 < K; k0 += BK) {
            // A tile: As[kk][m] = A[r0+m][k0+kk]
            {
                int m = tid >> 2;
                int kb = (tid & 3) * 4;
                long arow = (long)(r0 + m) * K;
                #pragma unroll
                for (int j = 0; j < 4; j++) {
                    int kk = kb + j;
                    As[kk][m] = (k0 + kk < K) ? A[arow + k0 + kk] : 0.f;
                }
            }
            // B tile: Bs[kk][n] = W[k0+kk][c0+n]
            {
                int kk = tid >> 4;
                int nb = (tid & 15) * 4;
                bool ok = (k0 + kk < K);
                const float* Wr = W + (long)(k0 + kk) * Dout + c0 + nb;
                #pragma unroll
                for (int j = 0; j < 4; j++) Bs[kk][nb + j] = ok ? Wr[j] : 0.f;
            }
            __syncthreads();
            #pragma unroll
            for (int kk = 0; kk < BK; kk++) {
                float a[4], bb[4];
                #pragma unroll
                for (int i = 0; i < 4; i++) a[i] = As[kk][tm * 4 + i];
                #pragma unroll
                for (int j = 0; j < 4; j++) bb[j] = Bs[kk][tn * 4 + j];
                #pragma unroll
                for (int i = 0; i < 4; i++)
                    #pragma unroll
                    for (int j = 0; j < 4; j++)
                        acc[i][j] += a[i] * bb[j];
            }
            __syncthreads();
        }
    }

    #pragma unroll
    for (int i = 0; i < 4; i++) {
        int r = r0 + tm * 4 + i;
        float* o = Out + (long)r * Dout + c0 + tn * 4;
        float4 v;
        #pragma unroll
        for (int j = 0; j < 4; j++) {
            float xv = acc[i][j] + bias[c0 + tn * 4 + j];
            ((float*)&v)[j] = lrelu(xv);
        }
        *(float4*)o = v;
    }
}

// ---------------------------------------------------------------------------
// segment max pooling over contiguous row ranges
// which==0: compound (start=g*40, len=40); which==1: protein (static LENS)
// ---------------------------------------------------------------------------
__global__ __launch_bounds__(256) void pool_max_kernel(
    const float* __restrict__ x, float* __restrict__ out, int D, int which)
{
    int g = blockIdx.x;
    int t = threadIdx.x;
    int start, len;
    if (which == 0) { start = g * 40; len = 40; }
    else {
        start = 512 * ((g + 1) / 2) + 1024 * (g / 2);
        len = (g % 2 == 0) ? 512 : 1024;
    }
    for (int c = t; c < D; c += 256) {
        float m = -INFINITY;
        for (int r = 0; r < len; r++)
            m = fmaxf(m, x[(long)(start + r) * D + c]);
        out[g * D + c] = m;
    }
}

// ---------------------------------------------------------------------------
// head: cfc/pfc -> concat -> fc1 -> out   (one block per graph)
// ---------------------------------------------------------------------------
__global__ __launch_bounds__(256) void head_kernel(
    const float* __restrict__ cpool, const float* __restrict__ ppool,
    const float* __restrict__ cfc_w, const float* __restrict__ cfc_b,
    const float* __restrict__ pfc_w, const float* __restrict__ pfc_b,
    const float* __restrict__ fc1_w, const float* __restrict__ fc1_b,
    const float* __restrict__ out_w, const float* __restrict__ out_b,
    float* __restrict__ out)
{
    __shared__ float cp[512], pp[512], cf[128], pf[128], h[256], red[256];
    int g = blockIdx.x, t = threadIdx.x;
    for (int i = t; i < 512; i += 256) {
        cp[i] = cpool[g * 512 + i];
        pp[i] = ppool[g * 512 + i];
    }
    __syncthreads();
    if (t < 128) {
        float a = cfc_b[t];
        for (int k = 0; k < 512; k++) a += cp[k] * cfc_w[k * 128 + t];
        cf[t] = lrelu(a);
    } else {
        int o = t - 128;
        float a = pfc_b[o];
        for (int k = 0; k < 512; k++) a += pp[k] * pfc_w[k * 128 + o];
        pf[o] = lrelu(a);
    }
    __syncthreads();
    {
        float a = fc1_b[t];
        for (int k = 0; k < 128; k++) a += cf[k] * fc1_w[k * 256 + t];
        for (int k = 0; k < 128; k++) a += pf[k] * fc1_w[(128 + k) * 256 + t];
        h[t] = lrelu(a);
    }
    __syncthreads();
    red[t] = h[t] * out_w[t];
    __syncthreads();
    for (int s = 128; s > 0; s >>= 1) {
        if (t < s) red[t] += red[t + s];
        __syncthreads();
    }
    if (t == 0) out[g] = red[0] + out_b[0];
}

// ---------------------------------------------------------------------------
// launch
// ---------------------------------------------------------------------------
extern "C" void kernel_launch(void* const* d_in, const int* in_sizes, int n_in,
                              void* d_out, int out_size, void* d_ws, size_t ws_size,
                              hipStream_t stream) {
    const float* seq_x      = (const float*)d_in[0];
    const float* compound_x = (const float*)d_in[1];
    const float* conv_w     = (const float*)d_in[2];
    const float* conv_b     = (const float*)d_in[3];
    const float* c1_wl = (const float*)d_in[4];
    const float* c1_bl = (const float*)d_in[5];
    const float* c1_wr = (const float*)d_in[6];
    const float* c2_wl = (const float*)d_in[7];
    const float* c2_bl = (const float*)d_in[8];
    const float* c2_wr = (const float*)d_in[9];
    const float* c3_wl = (const float*)d_in[10];
    const float* c3_bl = (const float*)d_in[11];
    const float* c3_wr = (const float*)d_in[12];
    const float* cfc_w = (const float*)d_in[13];
    const float* cfc_b = (const float*)d_in[14];
    const float* p1_wl = (const float*)d_in[15];
    const float* p1_bl = (const float*)d_in[16];
    const float* p1_wr = (const float*)d_in[17];
    const float* p2_wl = (const float*)d_in[18];
    const float* p2_bl = (const float*)d_in[19];
    const float* p2_wr = (const float*)d_in[20];
    const float* p3_wl = (const float*)d_in[21];
    const float* p3_bl = (const float*)d_in[22];
    const float* p3_wr = (const float*)d_in[23];
    const float* pfc_w = (const float*)d_in[24];
    const float* pfc_b = (const float*)d_in[25];
    const float* fc1_w = (const float*)d_in[26];
    const float* fc1_b = (const float*)d_in[27];
    const float* out_w = (const float*)d_in[28];
    const float* out_b = (const float*)d_in[29];
    const int* prot_gather = (const int*)d_in[30];
    const int* prot_src    = (const int*)d_in[31];
    const int* prot_tgt    = (const int*)d_in[32];
    const int* comp_src    = (const int*)d_in[33];
    const int* comp_tgt    = (const int*)d_in[34];

    float* out = (float*)d_out;

    // workspace layout
    size_t off = 0;
    auto alloc = [&](size_t bytes) -> char* {
        char* p = (char*)d_ws + off;
        off = (off + bytes + 255) & ~(size_t)255;
        return p;
    };
    float* pbufA = (float*)alloc((size_t)NP_TOT * 256 * 4);   // conv out(128) / p2 out(256)
    float* pbufB = (float*)alloc((size_t)NP_TOT * 512 * 4);   // p1 out(128) / p3 out(512)
    float* pagg  = (float*)alloc((size_t)NP_TOT * 256 * 4);
    float* cbufA = (float*)alloc((size_t)NC_TOT * 512 * 4);   // c1 out(128) / c3 out(512)
    float* cbufB = (float*)alloc((size_t)NC_TOT * 256 * 4);   // c2 out(256)
    float* cagg  = (float*)alloc((size_t)NC_TOT * 256 * 4);
    float* cpool = (float*)alloc(B_GRAPHS * 512 * 4);
    float* ppool = (float*)alloc(B_GRAPHS * 512 * 4);
    int* p_rowptr = (int*)alloc((NP_TOT + 1) * 4);
    int* p_cursor = (int*)alloc(NP_TOT * 4);
    int* p_csr    = (int*)alloc(EP_TOT * 4);
    int* c_rowptr = (int*)alloc((NC_TOT + 1) * 4);
    int* c_cursor = (int*)alloc(NC_TOT * 4);
    int* c_csr    = (int*)alloc(EC_TOT * 4);
    (void)ws_size; (void)n_in; (void)in_sizes; (void)out_size;

    // ---- protein CSR ----
    zero_int_kernel<<<(NP_TOT + 255) / 256, 256, 0, stream>>>(p_cursor, NP_TOT);
    hist_kernel<<<(EP_TOT + 255) / 256, 256, 0, stream>>>(prot_tgt, p_cursor, EP_TOT);
    exscan_kernel<<<1, 256, 0, stream>>>(p_cursor, p_rowptr, NP_TOT);
    zero_int_kernel<<<(NP_TOT + 255) / 256, 256, 0, stream>>>(p_cursor, NP_TOT);
    scatter_kernel<<<(EP_TOT + 255) / 256, 256, 0, stream>>>(prot_src, prot_tgt, p_rowptr, p_cursor, p_csr, EP_TOT);
    // ---- compound CSR ----
    zero_int_kernel<<<(NC_TOT + 255) / 256, 256, 0, stream>>>(c_cursor, NC_TOT);
    hist_kernel<<<(EC_TOT + 255) / 256, 256, 0, stream>>>(comp_tgt, c_cursor, EC_TOT);
    exscan_kernel<<<1, 256, 0, stream>>>(c_cursor, c_rowptr, NC_TOT);
    zero_int_kernel<<<(NC_TOT + 255) / 256, 256, 0, stream>>>(c_cursor, NC_TOT);
    scatter_kernel<<<(EC_TOT + 255) / 256, 256, 0, stream>>>(comp_src, comp_tgt, c_rowptr, c_cursor, c_csr, EC_TOT);

    // ---- conv (packed rows) -> pbufA [NP,128] ----
    conv1d_packed_kernel<<<(NP_TOT + CONV_ROWS - 1) / CONV_ROWS, 128, 0, stream>>>(
        seq_x, conv_w, conv_b, prot_gather, pbufA, NP_TOT);

    // ---- compound GNN ----
    sage_agg_kernel<<<(NC_TOT + 3) / 4, 256, 0, stream>>>(compound_x, c_rowptr, c_csr, cagg, NC_TOT, 78);
    sage_gemm_kernel<<<dim3(NC_TOT / 64, 128 / 64), 256, 0, stream>>>(
        cagg, c1_wl, compound_x, c1_wr, c1_bl, cbufA, NC_TOT, 78, 128);
    sage_agg_kernel<<<(NC_TOT + 3) / 4, 256, 0, stream>>>(cbufA, c_rowptr, c_csr, cagg, NC_TOT, 128);
    sage_gemm_kernel<<<dim3(NC_TOT / 64, 256 / 64), 256, 0, stream>>>(
        cagg, c2_wl, cbufA, c2_wr, c2_bl, cbufB, NC_TOT, 128, 256);
    sage_agg_kernel<<<(NC_TOT + 3) / 4, 256, 0, stream>>>(cbufB, c_rowptr, c_csr, cagg, NC_TOT, 256);
    sage_gemm_kernel<<<dim3(NC_TOT / 64, 512 / 64), 256, 0, stream>>>(
        cagg, c3_wl, cbufB, c3_wr, c3_bl, cbufA, NC_TOT, 256, 512);
    pool_max_kernel<<<B_GRAPHS, 256, 0, stream>>>(cbufA, cpool, 512, 0);

    // ---- protein GNN ----
    sage_agg_kernel<<<(NP_TOT + 3) / 4, 256, 0, stream>>>(pbufA, p_rowptr, p_csr, pagg, NP_TOT, 128);
    sage_gemm_kernel<<<dim3(NP_TOT / 64, 128 / 64), 256, 0, stream>>>(
        pagg, p1_wl, pbufA, p1_wr, p1_bl, pbufB, NP_TOT, 128, 128);
    sage_agg_kernel<<<(NP_TOT + 3) / 4, 256, 0, stream>>>(pbufB, p_rowptr, p_csr, pagg, NP_TOT, 128);
    sage_gemm_kernel<<<dim3(NP_TOT / 64, 256 / 64), 256, 0, stream>>>(
        pagg, p2_wl, pbufB, p2_wr, p2_bl, pbufA, NP_TOT, 128, 256);
    sage_agg_kernel<<<(NP_TOT + 3) / 4, 256, 0, stream>>>(pbufA, p_rowptr, p_csr, pagg, NP_TOT, 256);
    sage_gemm_kernel<<<dim3(NP_TOT / 64, 512 / 64), 256, 0, stream>>>(
        pagg, p3_wl, pbufA, p3_wr, p3_bl, pbufB, NP_TOT, 256, 512);
    pool_max_kernel<<<B_GRAPHS, 256, 0, stream>>>(pbufB, ppool, 512, 1);

    // ---- head ----
    head_kernel<<<B_GRAPHS, 256, 0, stream>>>(cpool, ppool, cfc_w, cfc_b, pfc_w, pfc_b,
                                              fc1_w, fc1_b, out_w, out_b, out);
}

// Round 2
// 1245.919 us; speedup vs baseline: 1.6039x; 1.6039x over previous
//
#include <hip/hip_runtime.h>
#include <hip/hip_bf16.h>

// ---------------------------------------------------------------------------
// Problem constants (from reference)
// ---------------------------------------------------------------------------
#define B_GRAPHS 64
#define LMAX 1024
#define NP_TOT 49152      // sum(LENS)
#define NC_TOT 2560       // 64*40
#define EP_TOT 393216     // 8 * NP
#define EC_TOT 10240      // 4 * NC

__device__ __forceinline__ float lrelu(float x) { return x > 0.f ? x : 0.01f * x; }

// ---------------------------------------------------------------------------
// small utility kernels
// ---------------------------------------------------------------------------
__global__ void zero_int_kernel(int* p, int n) {
    int i = blockIdx.x * blockDim.x + threadIdx.x;
    if (i < n) p[i] = 0;
}

__global__ void hist_kernel(const int* __restrict__ tgt, int* __restrict__ deg, int E) {
    int e = blockIdx.x * blockDim.x + threadIdx.x;
    if (e < E) atomicAdd(&deg[tgt[e]], 1);
}

// single-block exclusive scan; out has n+1 entries (out[n] = total)
__global__ void exscan_kernel(const int* __restrict__ in, int* __restrict__ out, int n) {
    __shared__ int part[256];
    int t = threadIdx.x;
    int chunk = (n + 255) / 256;
    int lo = t * chunk;
    int hi = lo + chunk; if (hi > n) hi = n;
    int s = 0;
    for (int i = lo; i < hi; i++) s += in[i];
    part[t] = s;
    __syncthreads();
    if (t == 0) {
        int run = 0;
        for (int i = 0; i < 256; i++) { int v = part[i]; part[i] = run; run += v; }
    }
    __syncthreads();
    int run = part[t];
    for (int i = lo; i < hi; i++) { out[i] = run; run += in[i]; }
    if (t == 255) out[n] = run;
}

__global__ void scatter_kernel(const int* __restrict__ src, const int* __restrict__ tgt,
                               const int* __restrict__ rowptr, int* __restrict__ cursor,
                               int* __restrict__ csr, int E) {
    int e = blockIdx.x * blockDim.x + threadIdx.x;
    if (e >= E) return;
    int t = tgt[e];
    int pos = atomicAdd(&cursor[t], 1);
    csr[rowptr[t] + pos] = src[e];
}

// ---------------------------------------------------------------------------
// conv1d, strip-mined: one block = 64 consecutive packed rows (never crosses
// a protein boundary: packed starts are multiples of 512). 256 threads,
// thread = (channel, rowgroup). One __syncthreads total.
// ---------------------------------------------------------------------------
#define CVROWS 64
__global__ __launch_bounds__(256) void conv_strip_kernel(
    const float* __restrict__ seq, const float* __restrict__ w,
    const float* __restrict__ bvec, const int* __restrict__ gather,
    float* __restrict__ out)
{
    __shared__ float ws[128 * 105];
    __shared__ float xs[(CVROWS + 4) * 21];
    int t = threadIdx.x;
    int row0 = blockIdx.x * CVROWS;
    for (int i = t; i < 128 * 105; i += 256) ws[i] = w[i];
    int g0 = gather[row0];
    int bb = g0 >> 10, l0 = g0 & (LMAX - 1);
    for (int i = t; i < (CVROWS + 4) * 21; i += 256) {
        int rr = i / 21, c = i - rr * 21;
        int l = l0 + rr - 2;
        xs[i] = ((unsigned)l < (unsigned)LMAX) ? seq[((long)bb * LMAX + l) * 21 + c] : 0.f;
    }
    __syncthreads();
    int ch = t & 127, rg = t >> 7;
    float bias = bvec[ch];
    const float* wo = ws + ch * 105;
    for (int r = rg * 32; r < rg * 32 + 32; ++r) {
        float acc = bias;
        #pragma unroll
        for (int c = 0; c < 21; ++c)
            #pragma unroll
            for (int k = 0; k < 5; ++k)
                acc += xs[(r + k) * 21 + c] * wo[c * 5 + k];
        out[(long)(row0 + r) * 128 + ch] = acc;
    }
}

// ---------------------------------------------------------------------------
// CSR aggregation, vectorized.
// ---------------------------------------------------------------------------
__global__ __launch_bounds__(256) void sage_agg256_kernel(
    const float* __restrict__ x, const int* __restrict__ rowptr,
    const int* __restrict__ csr, float* __restrict__ agg, int n)
{
    int node = (blockIdx.x * 256 + threadIdx.x) >> 6;
    int lane = threadIdx.x & 63;
    if (node >= n) return;
    int beg = rowptr[node], end = rowptr[node + 1];
    float4 acc = {0.f, 0.f, 0.f, 0.f};
    for (int j = beg; j < end; ++j) {
        int s = csr[j];
        float4 v = *(const float4*)(x + (long)s * 256 + lane * 4);
        acc.x += v.x; acc.y += v.y; acc.z += v.z; acc.w += v.w;
    }
    *(float4*)(agg + (long)node * 256 + lane * 4) = acc;
}

__global__ __launch_bounds__(256) void sage_agg128_kernel(
    const float* __restrict__ x, const int* __restrict__ rowptr,
    const int* __restrict__ csr, float* __restrict__ agg, int n)
{
    int node = (blockIdx.x * 256 + threadIdx.x) >> 5;   // 32 lanes per node
    int lane = threadIdx.x & 31;
    if (node >= n) return;
    int beg = rowptr[node], end = rowptr[node + 1];
    float4 acc = {0.f, 0.f, 0.f, 0.f};
    for (int j = beg; j < end; ++j) {
        int s = csr[j];
        float4 v = *(const float4*)(x + (long)s * 128 + lane * 4);
        acc.x += v.x; acc.y += v.y; acc.z += v.z; acc.w += v.w;
    }
    *(float4*)(agg + (long)node * 128 + lane * 4) = acc;
}

__global__ __launch_bounds__(256) void sage_agg78_kernel(
    const float* __restrict__ x, const int* __restrict__ rowptr,
    const int* __restrict__ csr, float* __restrict__ agg, int n)
{
    int node = (blockIdx.x * 256 + threadIdx.x) >> 6;
    int lane = threadIdx.x & 63;
    if (node >= n) return;
    int beg = rowptr[node], end = rowptr[node + 1];
    float a0 = 0.f, a1 = 0.f;
    for (int j = beg; j < end; ++j) {
        int s = csr[j];
        const float* xr = x + (long)s * 78;
        a0 += xr[lane];
        if (lane + 64 < 78) a1 += xr[lane + 64];
    }
    float* ar = agg + (long)node * 78;
    ar[lane] = a0;
    if (lane + 64 < 78) ar[lane + 64] = a1;
}

// ---------------------------------------------------------------------------
// fused dual GEMM: Out = lrelu(A0 @ W0 + A1 @ W1 + bias)
// BM=BN=128, BK=16, 256 threads, 8x8 per thread, split fragments (2-way max
// bank aliasing on all LDS phases). N%128==0, Dout%128==0; K arbitrary.
// ---------------------------------------------------------------------------
#define GBM 128
#define GBN 128
#define GBK 16
__global__ __launch_bounds__(256) void sage_gemm_kernel(
    const float* __restrict__ A0, const float* __restrict__ W0,
    const float* __restrict__ A1, const float* __restrict__ W1,
    const float* __restrict__ bias, float* __restrict__ Out,
    int N, int K, int Dout)
{
    __shared__ float As[GBK][GBM + 4];
    __shared__ float Bs[GBK][GBN];
    int tid = threadIdx.x;
    int r0 = blockIdx.x * GBM;
    int c0 = blockIdx.y * GBN;
    int tm = tid >> 4, tn = tid & 15;
    int ra = tm * 4, rb = 64 + tm * 4;
    int ca = tn * 4, cb = 64 + tn * 4;
    float acc[8][8] = {};
    bool k4 = (K & 3) == 0;

    for (int pass = 0; pass < 2; ++pass) {
        const float* A = pass ? A1 : A0;
        const float* W = pass ? W1 : W0;
        for (int k0 = 0; k0 < K; k0 += GBK) {
            // A tile -> As[kk][m] (transposed). thread: 2 float4 along K.
            {
                int row = tid >> 2;       // 0..63
                int kk0 = (tid & 3) * 4;  // 0,4,8,12
                #pragma unroll
                for (int h = 0; h < 2; ++h) {
                    int rr = row + h * 64;
                    float v[4];
                    if (k4 && (k0 + kk0 + 3 < K)) {
                        float4 t4 = *(const float4*)(A + (long)(r0 + rr) * K + k0 + kk0);
                        v[0] = t4.x; v[1] = t4.y; v[2] = t4.z; v[3] = t4.w;
                    } else {
                        #pragma unroll
                        for (int j = 0; j < 4; ++j)
                            v[j] = (k0 + kk0 + j < K) ? A[(long)(r0 + rr) * K + k0 + kk0 + j] : 0.f;
                    }
                    #pragma unroll
                    for (int j = 0; j < 4; ++j) As[kk0 + j][rr] = v[j];
                }
            }
            // B tile -> Bs[kk][n]. thread: 2 float4 along N.
            {
                int kk = tid >> 5;        // 0..7
                int cv = tid & 31;        // float4 col
                #pragma unroll
                for (int h = 0; h < 2; ++h) {
                    int kr = kk + h * 8;
                    float4 v = {0.f, 0.f, 0.f, 0.f};
                    if (k0 + kr < K)
                        v = *(const float4*)(W + (long)(k0 + kr) * Dout + c0 + cv * 4);
                    *(float4*)&Bs[kr][cv * 4] = v;
                }
            }
            __syncthreads();
            #pragma unroll
            for (int kk = 0; kk < GBK; ++kk) {
                float a[8], b[8];
                *(float4*)&a[0] = *(const float4*)&As[kk][ra];
                *(float4*)&a[4] = *(const float4*)&As[kk][rb];
                *(float4*)&b[0] = *(const float4*)&Bs[kk][ca];
                *(float4*)&b[4] = *(const float4*)&Bs[kk][cb];
                #pragma unroll
                for (int i = 0; i < 8; ++i)
                    #pragma unroll
                    for (int j = 0; j < 8; ++j)
                        acc[i][j] += a[i] * b[j];
            }
            __syncthreads();
        }
    }

    // epilogue
    #pragma unroll
    for (int i = 0; i < 8; ++i) {
        int r = r0 + (i < 4 ? ra + i : rb + i - 4);
        float* orow = Out + (long)r * Dout + c0;
        float4 v0, v1;
        #pragma unroll
        for (int j = 0; j < 4; ++j) {
            ((float*)&v0)[j] = lrelu(acc[i][j]     + bias[c0 + ca + j]);
            ((float*)&v1)[j] = lrelu(acc[i][j + 4] + bias[c0 + cb + j]);
        }
        *(float4*)(orow + ca) = v0;
        *(float4*)(orow + cb) = v1;
    }
}

// ---------------------------------------------------------------------------
// pooling
// ---------------------------------------------------------------------------
// compound: 40 rows per graph, trivial
__global__ __launch_bounds__(256) void pool_comp_kernel(
    const float* __restrict__ x, float* __restrict__ out)
{
    int g = blockIdx.x;
    int c = blockIdx.y * 256 + threadIdx.x;
    float m = -INFINITY;
    for (int r = 0; r < 40; ++r)
        m = fmaxf(m, x[(long)(g * 40 + r) * 512 + c]);
    out[g * 512 + c] = m;
}

// protein: 2-stage row-split
#define PSPLIT 4
__global__ __launch_bounds__(256) void pool_prot_partial_kernel(
    const float* __restrict__ x, float* __restrict__ part)
{
    int g = blockIdx.x, cb = blockIdx.y, s = blockIdx.z;
    int col = cb * 256 + threadIdx.x;
    int start = 512 * ((g + 1) / 2) + 1024 * (g / 2);
    int len = (g & 1) ? 1024 : 512;
    int chunk = len / PSPLIT;
    int r0 = s * chunk;
    float m = -INFINITY;
    #pragma unroll 4
    for (int r = 0; r < chunk; ++r)
        m = fmaxf(m, x[(long)(start + r0 + r) * 512 + col]);
    part[(long)(g * PSPLIT + s) * 512 + col] = m;
}

__global__ __launch_bounds__(256) void pool_prot_final_kernel(
    const float* __restrict__ part, float* __restrict__ out)
{
    int g = blockIdx.x;
    int col = blockIdx.y * 256 + threadIdx.x;
    float m = -INFINITY;
    #pragma unroll
    for (int s = 0; s < PSPLIT; ++s)
        m = fmaxf(m, part[(long)(g * PSPLIT + s) * 512 + col]);
    out[g * 512 + col] = m;
}

// ---------------------------------------------------------------------------
// head: cfc/pfc -> concat -> fc1 -> out   (one block per graph)
// ---------------------------------------------------------------------------
__global__ __launch_bounds__(256) void head_kernel(
    const float* __restrict__ cpool, const float* __restrict__ ppool,
    const float* __restrict__ cfc_w, const float* __restrict__ cfc_b,
    const float* __restrict__ pfc_w, const float* __restrict__ pfc_b,
    const float* __restrict__ fc1_w, const float* __restrict__ fc1_b,
    const float* __restrict__ out_w, const float* __restrict__ out_b,
    float* __restrict__ out)
{
    __shared__ float cp[512], pp[512], cf[128], pf[128], h[256], red[256];
    int g = blockIdx.x, t = threadIdx.x;
    for (int i = t; i < 512; i += 256) {
        cp[i] = cpool[g * 512 + i];
        pp[i] = ppool[g * 512 + i];
    }
    __syncthreads();
    if (t < 128) {
        float a = cfc_b[t];
        for (int k = 0; k < 512; k++) a += cp[k] * cfc_w[k * 128 + t];
        cf[t] = lrelu(a);
    } else {
        int o = t - 128;
        float a = pfc_b[o];
        for (int k = 0; k < 512; k++) a += pp[k] * pfc_w[k * 128 + o];
        pf[o] = lrelu(a);
    }
    __syncthreads();
    {
        float a = fc1_b[t];
        for (int k = 0; k < 128; k++) a += cf[k] * fc1_w[k * 256 + t];
        for (int k = 0; k < 128; k++) a += pf[k] * fc1_w[(128 + k) * 256 + t];
        h[t] = lrelu(a);
    }
    __syncthreads();
    red[t] = h[t] * out_w[t];
    __syncthreads();
    for (int s = 128; s > 0; s >>= 1) {
        if (t < s) red[t] += red[t + s];
        __syncthreads();
    }
    if (t == 0) out[g] = red[0] + out_b[0];
}

// ---------------------------------------------------------------------------
// launch
// ---------------------------------------------------------------------------
extern "C" void kernel_launch(void* const* d_in, const int* in_sizes, int n_in,
                              void* d_out, int out_size, void* d_ws, size_t ws_size,
                              hipStream_t stream) {
    const float* seq_x      = (const float*)d_in[0];
    const float* compound_x = (const float*)d_in[1];
    const float* conv_w     = (const float*)d_in[2];
    const float* conv_b     = (const float*)d_in[3];
    const float* c1_wl = (const float*)d_in[4];
    const float* c1_bl = (const float*)d_in[5];
    const float* c1_wr = (const float*)d_in[6];
    const float* c2_wl = (const float*)d_in[7];
    const float* c2_bl = (const float*)d_in[8];
    const float* c2_wr = (const float*)d_in[9];
    const float* c3_wl = (const float*)d_in[10];
    const float* c3_bl = (const float*)d_in[11];
    const float* c3_wr = (const float*)d_in[12];
    const float* cfc_w = (const float*)d_in[13];
    const float* cfc_b = (const float*)d_in[14];
    const float* p1_wl = (const float*)d_in[15];
    const float* p1_bl = (const float*)d_in[16];
    const float* p1_wr = (const float*)d_in[17];
    const float* p2_wl = (const float*)d_in[18];
    const float* p2_bl = (const float*)d_in[19];
    const float* p2_wr = (const float*)d_in[20];
    const float* p3_wl = (const float*)d_in[21];
    const float* p3_bl = (const float*)d_in[22];
    const float* p3_wr = (const float*)d_in[23];
    const float* pfc_w = (const float*)d_in[24];
    const float* pfc_b = (const float*)d_in[25];
    const float* fc1_w = (const float*)d_in[26];
    const float* fc1_b = (const float*)d_in[27];
    const float* out_w = (const float*)d_in[28];
    const float* out_b = (const float*)d_in[29];
    const int* prot_gather = (const int*)d_in[30];
    const int* prot_src    = (const int*)d_in[31];
    const int* prot_tgt    = (const int*)d_in[32];
    const int* comp_src    = (const int*)d_in[33];
    const int* comp_tgt    = (const int*)d_in[34];

    float* out = (float*)d_out;

    // workspace layout
    size_t off = 0;
    auto alloc = [&](size_t bytes) -> char* {
        char* p = (char*)d_ws + off;
        off = (off + bytes + 255) & ~(size_t)255;
        return p;
    };
    float* pbufA = (float*)alloc((size_t)NP_TOT * 256 * 4);   // conv out(128) / p2 out(256)
    float* pbufB = (float*)alloc((size_t)NP_TOT * 512 * 4);   // p1 out(128) / p3 out(512)
    float* pagg  = (float*)alloc((size_t)NP_TOT * 256 * 4);
    float* cbufA = (float*)alloc((size_t)NC_TOT * 512 * 4);   // c1 out(128) / c3 out(512)
    float* cbufB = (float*)alloc((size_t)NC_TOT * 256 * 4);   // c2 out(256)
    float* cagg  = (float*)alloc((size_t)NC_TOT * 256 * 4);
    float* cpool = (float*)alloc(B_GRAPHS * 512 * 4);
    float* ppool = (float*)alloc(B_GRAPHS * 512 * 4);
    float* ppart = (float*)alloc((size_t)B_GRAPHS * PSPLIT * 512 * 4);
    int* p_rowptr = (int*)alloc((NP_TOT + 1) * 4);
    int* p_cursor = (int*)alloc(NP_TOT * 4);
    int* p_csr    = (int*)alloc(EP_TOT * 4);
    int* c_rowptr = (int*)alloc((NC_TOT + 1) * 4);
    int* c_cursor = (int*)alloc(NC_TOT * 4);
    int* c_csr    = (int*)alloc(EC_TOT * 4);
    (void)ws_size; (void)n_in; (void)in_sizes; (void)out_size;

    // ---- protein CSR ----
    zero_int_kernel<<<(NP_TOT + 255) / 256, 256, 0, stream>>>(p_cursor, NP_TOT);
    hist_kernel<<<(EP_TOT + 255) / 256, 256, 0, stream>>>(prot_tgt, p_cursor, EP_TOT);
    exscan_kernel<<<1, 256, 0, stream>>>(p_cursor, p_rowptr, NP_TOT);
    zero_int_kernel<<<(NP_TOT + 255) / 256, 256, 0, stream>>>(p_cursor, NP_TOT);
    scatter_kernel<<<(EP_TOT + 255) / 256, 256, 0, stream>>>(prot_src, prot_tgt, p_rowptr, p_cursor, p_csr, EP_TOT);
    // ---- compound CSR ----
    zero_int_kernel<<<(NC_TOT + 255) / 256, 256, 0, stream>>>(c_cursor, NC_TOT);
    hist_kernel<<<(EC_TOT + 255) / 256, 256, 0, stream>>>(comp_tgt, c_cursor, EC_TOT);
    exscan_kernel<<<1, 256, 0, stream>>>(c_cursor, c_rowptr, NC_TOT);
    zero_int_kernel<<<(NC_TOT + 255) / 256, 256, 0, stream>>>(c_cursor, NC_TOT);
    scatter_kernel<<<(EC_TOT + 255) / 256, 256, 0, stream>>>(comp_src, comp_tgt, c_rowptr, c_cursor, c_csr, EC_TOT);

    // ---- conv (packed rows) -> pbufA [NP,128] ----
    conv_strip_kernel<<<NP_TOT / CVROWS, 256, 0, stream>>>(seq_x, conv_w, conv_b, prot_gather, pbufA);

    // ---- compound GNN ----
    sage_agg78_kernel<<<(NC_TOT + 3) / 4, 256, 0, stream>>>(compound_x, c_rowptr, c_csr, cagg, NC_TOT);
    sage_gemm_kernel<<<dim3(NC_TOT / GBM, 128 / GBN), 256, 0, stream>>>(
        cagg, c1_wl, compound_x, c1_wr, c1_bl, cbufA, NC_TOT, 78, 128);
    sage_agg128_kernel<<<(NC_TOT + 7) / 8, 256, 0, stream>>>(cbufA, c_rowptr, c_csr, cagg, NC_TOT);
    sage_gemm_kernel<<<dim3(NC_TOT / GBM, 256 / GBN), 256, 0, stream>>>(
        cagg, c2_wl, cbufA, c2_wr, c2_bl, cbufB, NC_TOT, 128, 256);
    sage_agg256_kernel<<<(NC_TOT + 3) / 4, 256, 0, stream>>>(cbufB, c_rowptr, c_csr, cagg, NC_TOT);
    sage_gemm_kernel<<<dim3(NC_TOT / GBM, 512 / GBN), 256, 0, stream>>>(
        cagg, c3_wl, cbufB, c3_wr, c3_bl, cbufA, NC_TOT, 256, 512);
    pool_comp_kernel<<<dim3(B_GRAPHS, 2), 256, 0, stream>>>(cbufA, cpool);

    // ---- protein GNN ----
    sage_agg128_kernel<<<(NP_TOT + 7) / 8, 256, 0, stream>>>(pbufA, p_rowptr, p_csr, pagg, NP_TOT);
    sage_gemm_kernel<<<dim3(NP_TOT / GBM, 128 / GBN), 256, 0, stream>>>(
        pagg, p1_wl, pbufA, p1_wr, p1_bl, pbufB, NP_TOT, 128, 128);
    sage_agg128_kernel<<<(NP_TOT + 7) / 8, 256, 0, stream>>>(pbufB, p_rowptr, p_csr, pagg, NP_TOT);
    sage_gemm_kernel<<<dim3(NP_TOT / GBM, 256 / GBN), 256, 0, stream>>>(
        pagg, p2_wl, pbufB, p2_wr, p2_bl, pbufA, NP_TOT, 128, 256);
    sage_agg256_kernel<<<(NP_TOT + 3) / 4, 256, 0, stream>>>(pbufA, p_rowptr, p_csr, pagg, NP_TOT);
    sage_gemm_kernel<<<dim3(NP_TOT / GBM, 512 / GBN), 256, 0, stream>>>(
        pagg, p3_wl, pbufA, p3_wr, p3_bl, pbufB, NP_TOT, 256, 512);
    pool_prot_partial_kernel<<<dim3(B_GRAPHS, 2, PSPLIT), 256, 0, stream>>>(pbufB, ppart);
    pool_prot_final_kernel<<<dim3(B_GRAPHS, 2), 256, 0, stream>>>(ppart, ppool);

    // ---- head ----
    head_kernel<<<B_GRAPHS, 256, 0, stream>>>(cpool, ppool, cfc_w, cfc_b, pfc_w, pfc_b,
                                              fc1_w, fc1_b, out_w, out_b, out);
}

// Round 3
// 685.680 us; speedup vs baseline: 2.9145x; 1.8171x over previous
//
#include <hip/hip_runtime.h>
#include <hip/hip_fp16.h>

// ---------------------------------------------------------------------------
// Problem constants (from reference)
// ---------------------------------------------------------------------------
#define B_GRAPHS 64
#define LMAX 1024
#define NP_TOT 49152      // sum(LENS)
#define NC_TOT 2560       // 64*40
#define EP_TOT 393216     // 8 * NP
#define EC_TOT 10240      // 4 * NC

typedef _Float16 f16x8 __attribute__((ext_vector_type(8)));
typedef _Float16 f16x4 __attribute__((ext_vector_type(4)));
typedef _Float16 f16x2 __attribute__((ext_vector_type(2)));
typedef float    f32x4 __attribute__((ext_vector_type(4)));

__device__ __forceinline__ float lrelu(float x) { return x > 0.f ? x : 0.01f * x; }

// ---------------------------------------------------------------------------
// small utility kernels (CSR build)
// ---------------------------------------------------------------------------
__global__ void zero_int_kernel(int* p, int n) {
    int i = blockIdx.x * blockDim.x + threadIdx.x;
    if (i < n) p[i] = 0;
}

__global__ void hist_kernel(const int* __restrict__ tgt, int* __restrict__ deg, int E) {
    int e = blockIdx.x * blockDim.x + threadIdx.x;
    if (e < E) atomicAdd(&deg[tgt[e]], 1);
}

__global__ void exscan_kernel(const int* __restrict__ in, int* __restrict__ out, int n) {
    __shared__ int part[256];
    int t = threadIdx.x;
    int chunk = (n + 255) / 256;
    int lo = t * chunk;
    int hi = lo + chunk; if (hi > n) hi = n;
    int s = 0;
    for (int i = lo; i < hi; i++) s += in[i];
    part[t] = s;
    __syncthreads();
    if (t == 0) {
        int run = 0;
        for (int i = 0; i < 256; i++) { int v = part[i]; part[i] = run; run += v; }
    }
    __syncthreads();
    int run = part[t];
    for (int i = lo; i < hi; i++) { out[i] = run; run += in[i]; }
    if (t == 255) out[n] = run;
}

__global__ void scatter_kernel(const int* __restrict__ src, const int* __restrict__ tgt,
                               const int* __restrict__ rowptr, int* __restrict__ cursor,
                               int* __restrict__ csr, int E) {
    int e = blockIdx.x * blockDim.x + threadIdx.x;
    if (e >= E) return;
    int t = tgt[e];
    int pos = atomicAdd(&cursor[t], 1);
    csr[rowptr[t] + pos] = src[e];
}

// ---------------------------------------------------------------------------
// weight prep: in f32 [K][D]  ->  out f16 [D][Kp] (transposed, zero-padded K)
// ---------------------------------------------------------------------------
__global__ void wprep_kernel(const float* __restrict__ in, _Float16* __restrict__ out,
                             int K, int D, int Kp) {
    int d = blockIdx.x;
    int k = blockIdx.y * 256 + threadIdx.x;
    if (k >= Kp) return;
    float v = (k < K) ? in[(long)k * D + d] : 0.f;
    out[(long)d * Kp + k] = (_Float16)v;
}

// compound_x f32 [2560][78] -> f16 [2560][96] zero-padded
__global__ void cx_conv_kernel(const float* __restrict__ in, _Float16* __restrict__ out) {
    int i = blockIdx.x * 256 + threadIdx.x;
    if (i >= NC_TOT * 96) return;
    int r = i / 96, k = i - r * 96;
    out[i] = (_Float16)(k < 78 ? in[r * 78 + k] : 0.f);
}

// ---------------------------------------------------------------------------
// conv1d, strip-mined: one block = 64 consecutive packed rows. fp16 output.
// ---------------------------------------------------------------------------
#define CVROWS 64
__global__ __launch_bounds__(256) void conv_strip_kernel(
    const float* __restrict__ seq, const float* __restrict__ w,
    const float* __restrict__ bvec, const int* __restrict__ gather,
    _Float16* __restrict__ out)
{
    __shared__ float ws[128 * 105];
    __shared__ float xs[(CVROWS + 4) * 21];
    int t = threadIdx.x;
    int row0 = blockIdx.x * CVROWS;
    for (int i = t; i < 128 * 105; i += 256) ws[i] = w[i];
    int g0 = gather[row0];
    int bb = g0 >> 10, l0 = g0 & (LMAX - 1);
    for (int i = t; i < (CVROWS + 4) * 21; i += 256) {
        int rr = i / 21, c = i - rr * 21;
        int l = l0 + rr - 2;
        xs[i] = ((unsigned)l < (unsigned)LMAX) ? seq[((long)bb * LMAX + l) * 21 + c] : 0.f;
    }
    __syncthreads();
    int ch = t & 127, rg = t >> 7;
    float bias = bvec[ch];
    const float* wo = ws + ch * 105;
    for (int r = rg * 32; r < rg * 32 + 32; ++r) {
        float acc = bias;
        #pragma unroll
        for (int c = 0; c < 21; ++c)
            #pragma unroll
            for (int k = 0; k < 5; ++k)
                acc += xs[(r + k) * 21 + c] * wo[c * 5 + k];
        out[(long)(row0 + r) * 128 + ch] = (_Float16)acc;
    }
}

// ---------------------------------------------------------------------------
// CSR aggregation, fp16 in/out, f32 accumulate
// ---------------------------------------------------------------------------
__global__ __launch_bounds__(256) void agg256_f16_kernel(
    const _Float16* __restrict__ x, const int* __restrict__ rowptr,
    const int* __restrict__ csr, _Float16* __restrict__ agg, int n)
{
    int node = (blockIdx.x * 256 + threadIdx.x) >> 6;
    int lane = threadIdx.x & 63;
    if (node >= n) return;
    int beg = rowptr[node], end = rowptr[node + 1];
    float a0 = 0.f, a1 = 0.f, a2 = 0.f, a3 = 0.f;
    for (int j = beg; j < end; ++j) {
        int s = csr[j];
        f16x4 v = *(const f16x4*)(x + (long)s * 256 + lane * 4);
        a0 += (float)v[0]; a1 += (float)v[1]; a2 += (float)v[2]; a3 += (float)v[3];
    }
    f16x4 o; o[0] = (_Float16)a0; o[1] = (_Float16)a1; o[2] = (_Float16)a2; o[3] = (_Float16)a3;
    *(f16x4*)(agg + (long)node * 256 + lane * 4) = o;
}

__global__ __launch_bounds__(256) void agg128_f16_kernel(
    const _Float16* __restrict__ x, const int* __restrict__ rowptr,
    const int* __restrict__ csr, _Float16* __restrict__ agg, int n)
{
    int node = (blockIdx.x * 256 + threadIdx.x) >> 5;
    int lane = threadIdx.x & 31;
    if (node >= n) return;
    int beg = rowptr[node], end = rowptr[node + 1];
    float a0 = 0.f, a1 = 0.f, a2 = 0.f, a3 = 0.f;
    for (int j = beg; j < end; ++j) {
        int s = csr[j];
        f16x4 v = *(const f16x4*)(x + (long)s * 128 + lane * 4);
        a0 += (float)v[0]; a1 += (float)v[1]; a2 += (float)v[2]; a3 += (float)v[3];
    }
    f16x4 o; o[0] = (_Float16)a0; o[1] = (_Float16)a1; o[2] = (_Float16)a2; o[3] = (_Float16)a3;
    *(f16x4*)(agg + (long)node * 128 + lane * 4) = o;
}

__global__ __launch_bounds__(256) void agg96_f16_kernel(
    const _Float16* __restrict__ x, const int* __restrict__ rowptr,
    const int* __restrict__ csr, _Float16* __restrict__ agg, int n)
{
    int node = (blockIdx.x * 256 + threadIdx.x) >> 6;
    int lane = threadIdx.x & 63;
    if (node >= n) return;
    if (lane < 48) {
        int beg = rowptr[node], end = rowptr[node + 1];
        float a0 = 0.f, a1 = 0.f;
        for (int j = beg; j < end; ++j) {
            int s = csr[j];
            f16x2 v = *(const f16x2*)(x + (long)s * 96 + lane * 2);
            a0 += (float)v[0]; a1 += (float)v[1];
        }
        f16x2 o; o[0] = (_Float16)a0; o[1] = (_Float16)a1;
        *(f16x2*)(agg + (long)node * 96 + lane * 2) = o;
    }
}

// ---------------------------------------------------------------------------
// fused dual MFMA GEMM (fp16 in, f32 accum, fp16 out):
//   Out = lrelu(A0 @ W0 + A1 @ W1 + bias)
// A: [N][K] f16, WT: [D][K] f16 (pre-transposed), Out: [N][D] f16.
// 128x128 tile, 256 threads = 4 waves (2x2), 4x4 16x16x32 frags per wave.
// LDS chunk-swizzled (c ^= row&3) -> conflict-free b128 read/write.
// Requires: N%128==0, D%128==0, K%32==0.
// ---------------------------------------------------------------------------
__global__ __launch_bounds__(256) void gemm_f16_kernel(
    const _Float16* __restrict__ A0, const _Float16* __restrict__ WT0,
    const _Float16* __restrict__ A1, const _Float16* __restrict__ WT1,
    const float* __restrict__ bias, _Float16* __restrict__ Out,
    int N, int K, int D)
{
    __shared__ _Float16 Asm[128 * 32];
    __shared__ _Float16 Bsm[128 * 32];
    const int tid = threadIdx.x;
    const int wave = tid >> 6, lane = tid & 63;
    const int wr = wave >> 1, wc = wave & 1;
    const int l15 = lane & 15, lk = lane >> 4;
    const long r0 = (long)blockIdx.x * 128;
    const long c0 = (long)blockIdx.y * 128;

    // staging assignment: thread -> (row srow, 16B chunk sc), rows srow & srow+64
    const int srow = tid >> 2, sc = tid & 3;
    const int w0 = srow * 32 + ((sc ^ (srow & 3)) * 8);
    const int w1 = w0 + 64 * 32;      // (srow+64)&3 == srow&3

    // fragment read offsets (constant across K-steps)
    int aoff[4], boff[4];
    #pragma unroll
    for (int m = 0; m < 4; ++m) {
        int row = wr * 64 + m * 16 + l15;
        aoff[m] = row * 32 + ((lk ^ (row & 3)) * 8);
        int col = wc * 64 + m * 16 + l15;
        boff[m] = col * 32 + ((lk ^ (col & 3)) * 8);
    }

    f32x4 acc[4][4];
    #pragma unroll
    for (int m = 0; m < 4; ++m)
        #pragma unroll
        for (int n = 0; n < 4; ++n)
            #pragma unroll
            for (int i = 0; i < 4; ++i) acc[m][n][i] = 0.f;

    const int ksteps = K >> 5;
    const int S = ksteps * 2;

    // prologue: load step 0 (pass 0, k0 = 0)
    f16x8 av0, av1, bv0, bv1;
    {
        const long kb = sc * 8;
        av0 = *(const f16x8*)(A0  + (r0 + srow) * K + kb);
        av1 = *(const f16x8*)(A0  + (r0 + srow + 64) * K + kb);
        bv0 = *(const f16x8*)(WT0 + (c0 + srow) * K + kb);
        bv1 = *(const f16x8*)(WT0 + (c0 + srow + 64) * K + kb);
    }

    for (int s = 0; s < S; ++s) {
        __syncthreads();                      // LDS free (prev compute done)
        *(f16x8*)(Asm + w0) = av0;
        *(f16x8*)(Asm + w1) = av1;
        *(f16x8*)(Bsm + w0) = bv0;
        *(f16x8*)(Bsm + w1) = bv1;
        __syncthreads();                      // tile ready
        if (s + 1 < S) {                      // prefetch next tile (overlaps MFMA)
            int s1 = s + 1;
            int pass = (s1 >= ksteps) ? 1 : 0;
            long kb = (long)(s1 - pass * ksteps) * 32 + sc * 8;
            const _Float16* Ax = pass ? A1 : A0;
            const _Float16* Wx = pass ? WT1 : WT0;
            av0 = *(const f16x8*)(Ax + (r0 + srow) * K + kb);
            av1 = *(const f16x8*)(Ax + (r0 + srow + 64) * K + kb);
            bv0 = *(const f16x8*)(Wx + (c0 + srow) * K + kb);
            bv1 = *(const f16x8*)(Wx + (c0 + srow + 64) * K + kb);
        }
        f16x8 af[4], bf[4];
        #pragma unroll
        for (int m = 0; m < 4; ++m) af[m] = *(const f16x8*)(Asm + aoff[m]);
        #pragma unroll
        for (int n = 0; n < 4; ++n) bf[n] = *(const f16x8*)(Bsm + boff[n]);
        #pragma unroll
        for (int m = 0; m < 4; ++m)
            #pragma unroll
            for (int n = 0; n < 4; ++n)
                acc[m][n] = __builtin_amdgcn_mfma_f32_16x16x32_f16(af[m], bf[n], acc[m][n], 0, 0, 0);
    }

    // epilogue: bias + lrelu + fp16 store
    float bn[4]; int coln[4];
    #pragma unroll
    for (int n = 0; n < 4; ++n) {
        coln[n] = (int)c0 + wc * 64 + n * 16 + l15;
        bn[n] = bias[coln[n]];
    }
    #pragma unroll
    for (int m = 0; m < 4; ++m) {
        long rowb = r0 + wr * 64 + m * 16 + lk * 4;
        #pragma unroll
        for (int i = 0; i < 4; ++i) {
            long row = rowb + i;
            #pragma unroll
            for (int n = 0; n < 4; ++n) {
                float v = acc[m][n][i] + bn[n];
                v = v > 0.f ? v : 0.01f * v;
                Out[row * D + coln[n]] = (_Float16)v;
            }
        }
    }
}

// ---------------------------------------------------------------------------
// pooling (fp16 input, f32 output)
// ---------------------------------------------------------------------------
__global__ __launch_bounds__(256) void pool_comp_kernel(
    const _Float16* __restrict__ x, float* __restrict__ out)
{
    int g = blockIdx.x;
    int c = blockIdx.y * 256 + threadIdx.x;
    float m = -INFINITY;
    for (int r = 0; r < 40; ++r)
        m = fmaxf(m, (float)x[(long)(g * 40 + r) * 512 + c]);
    out[g * 512 + c] = m;
}

#define PSPLIT 4
__global__ __launch_bounds__(256) void pool_prot_partial_kernel(
    const _Float16* __restrict__ x, float* __restrict__ part)
{
    int g = blockIdx.x, cb = blockIdx.y, s = blockIdx.z;
    int col = cb * 256 + threadIdx.x;
    int start = 512 * ((g + 1) / 2) + 1024 * (g / 2);
    int len = (g & 1) ? 1024 : 512;
    int chunk = len / PSPLIT;
    int r0 = s * chunk;
    float m = -INFINITY;
    #pragma unroll 4
    for (int r = 0; r < chunk; ++r)
        m = fmaxf(m, (float)x[(long)(start + r0 + r) * 512 + col]);
    part[(long)(g * PSPLIT + s) * 512 + col] = m;
}

__global__ __launch_bounds__(256) void pool_prot_final_kernel(
    const float* __restrict__ part, float* __restrict__ out)
{
    int g = blockIdx.x;
    int col = blockIdx.y * 256 + threadIdx.x;
    float m = -INFINITY;
    #pragma unroll
    for (int s = 0; s < PSPLIT; ++s)
        m = fmaxf(m, part[(long)(g * PSPLIT + s) * 512 + col]);
    out[g * 512 + col] = m;
}

// ---------------------------------------------------------------------------
// head: cfc/pfc -> concat -> fc1 -> out   (one block per graph, f32)
// ---------------------------------------------------------------------------
__global__ __launch_bounds__(256) void head_kernel(
    const float* __restrict__ cpool, const float* __restrict__ ppool,
    const float* __restrict__ cfc_w, const float* __restrict__ cfc_b,
    const float* __restrict__ pfc_w, const float* __restrict__ pfc_b,
    const float* __restrict__ fc1_w, const float* __restrict__ fc1_b,
    const float* __restrict__ out_w, const float* __restrict__ out_b,
    float* __restrict__ out)
{
    __shared__ float cp[512], pp[512], cf[128], pf[128], h[256], red[256];
    int g = blockIdx.x, t = threadIdx.x;
    for (int i = t; i < 512; i += 256) {
        cp[i] = cpool[g * 512 + i];
        pp[i] = ppool[g * 512 + i];
    }
    __syncthreads();
    if (t < 128) {
        float a = cfc_b[t];
        for (int k = 0; k < 512; k++) a += cp[k] * cfc_w[k * 128 + t];
        cf[t] = lrelu(a);
    } else {
        int o = t - 128;
        float a = pfc_b[o];
        for (int k = 0; k < 512; k++) a += pp[k] * pfc_w[k * 128 + o];
        pf[o] = lrelu(a);
    }
    __syncthreads();
    {
        float a = fc1_b[t];
        for (int k = 0; k < 128; k++) a += cf[k] * fc1_w[k * 256 + t];
        for (int k = 0; k < 128; k++) a += pf[k] * fc1_w[(128 + k) * 256 + t];
        h[t] = lrelu(a);
    }
    __syncthreads();
    red[t] = h[t] * out_w[t];
    __syncthreads();
    for (int s = 128; s > 0; s >>= 1) {
        if (t < s) red[t] += red[t + s];
        __syncthreads();
    }
    if (t == 0) out[g] = red[0] + out_b[0];
}

// ---------------------------------------------------------------------------
// launch
// ---------------------------------------------------------------------------
extern "C" void kernel_launch(void* const* d_in, const int* in_sizes, int n_in,
                              void* d_out, int out_size, void* d_ws, size_t ws_size,
                              hipStream_t stream) {
    const float* seq_x      = (const float*)d_in[0];
    const float* compound_x = (const float*)d_in[1];
    const float* conv_w     = (const float*)d_in[2];
    const float* conv_b     = (const float*)d_in[3];
    const float* c1_wl = (const float*)d_in[4];
    const float* c1_bl = (const float*)d_in[5];
    const float* c1_wr = (const float*)d_in[6];
    const float* c2_wl = (const float*)d_in[7];
    const float* c2_bl = (const float*)d_in[8];
    const float* c2_wr = (const float*)d_in[9];
    const float* c3_wl = (const float*)d_in[10];
    const float* c3_bl = (const float*)d_in[11];
    const float* c3_wr = (const float*)d_in[12];
    const float* cfc_w = (const float*)d_in[13];
    const float* cfc_b = (const float*)d_in[14];
    const float* p1_wl = (const float*)d_in[15];
    const float* p1_bl = (const float*)d_in[16];
    const float* p1_wr = (const float*)d_in[17];
    const float* p2_wl = (const float*)d_in[18];
    const float* p2_bl = (const float*)d_in[19];
    const float* p2_wr = (const float*)d_in[20];
    const float* p3_wl = (const float*)d_in[21];
    const float* p3_bl = (const float*)d_in[22];
    const float* p3_wr = (const float*)d_in[23];
    const float* pfc_w = (const float*)d_in[24];
    const float* pfc_b = (const float*)d_in[25];
    const float* fc1_w = (const float*)d_in[26];
    const float* fc1_b = (const float*)d_in[27];
    const float* out_w = (const float*)d_in[28];
    const float* out_b = (const float*)d_in[29];
    const int* prot_gather = (const int*)d_in[30];
    const int* prot_src    = (const int*)d_in[31];
    const int* prot_tgt    = (const int*)d_in[32];
    const int* comp_src    = (const int*)d_in[33];
    const int* comp_tgt    = (const int*)d_in[34];

    float* out = (float*)d_out;

    // workspace layout
    size_t off = 0;
    auto alloc = [&](size_t bytes) -> char* {
        char* p = (char*)d_ws + off;
        off = (off + bytes + 255) & ~(size_t)255;
        return p;
    };
    // fp16 activation buffers
    _Float16* pconv = (_Float16*)alloc((size_t)NP_TOT * 128 * 2);
    _Float16* pagg  = (_Float16*)alloc((size_t)NP_TOT * 256 * 2);
    _Float16* pl1   = (_Float16*)alloc((size_t)NP_TOT * 128 * 2);
    _Float16* pl2   = (_Float16*)alloc((size_t)NP_TOT * 256 * 2);
    _Float16* pl3   = (_Float16*)alloc((size_t)NP_TOT * 512 * 2);
    _Float16* cxp   = (_Float16*)alloc((size_t)NC_TOT * 96 * 2);
    _Float16* cagg  = (_Float16*)alloc((size_t)NC_TOT * 256 * 2);
    _Float16* cl1   = (_Float16*)alloc((size_t)NC_TOT * 128 * 2);
    _Float16* cl2   = (_Float16*)alloc((size_t)NC_TOT * 256 * 2);
    _Float16* cl3   = (_Float16*)alloc((size_t)NC_TOT * 512 * 2);
    // fp16 transposed weights [D][Kp]
    _Float16* wt_p1l = (_Float16*)alloc(128 * 128 * 2);
    _Float16* wt_p1r = (_Float16*)alloc(128 * 128 * 2);
    _Float16* wt_p2l = (_Float16*)alloc(256 * 128 * 2);
    _Float16* wt_p2r = (_Float16*)alloc(256 * 128 * 2);
    _Float16* wt_p3l = (_Float16*)alloc(512 * 256 * 2);
    _Float16* wt_p3r = (_Float16*)alloc(512 * 256 * 2);
    _Float16* wt_c1l = (_Float16*)alloc(128 * 96 * 2);
    _Float16* wt_c1r = (_Float16*)alloc(128 * 96 * 2);
    _Float16* wt_c2l = (_Float16*)alloc(256 * 128 * 2);
    _Float16* wt_c2r = (_Float16*)alloc(256 * 128 * 2);
    _Float16* wt_c3l = (_Float16*)alloc(512 * 256 * 2);
    _Float16* wt_c3r = (_Float16*)alloc(512 * 256 * 2);
    // pools (f32)
    float* cpool = (float*)alloc(B_GRAPHS * 512 * 4);
    float* ppool = (float*)alloc(B_GRAPHS * 512 * 4);
    float* ppart = (float*)alloc((size_t)B_GRAPHS * PSPLIT * 512 * 4);
    // CSR
    int* p_rowptr = (int*)alloc((NP_TOT + 1) * 4);
    int* p_cursor = (int*)alloc(NP_TOT * 4);
    int* p_csr    = (int*)alloc(EP_TOT * 4);
    int* c_rowptr = (int*)alloc((NC_TOT + 1) * 4);
    int* c_cursor = (int*)alloc(NC_TOT * 4);
    int* c_csr    = (int*)alloc(EC_TOT * 4);
    (void)ws_size; (void)n_in; (void)in_sizes; (void)out_size;

    // ---- weight prep + compound input conversion ----
    wprep_kernel<<<dim3(128, 1), 256, 0, stream>>>(p1_wl, wt_p1l, 128, 128, 128);
    wprep_kernel<<<dim3(128, 1), 256, 0, stream>>>(p1_wr, wt_p1r, 128, 128, 128);
    wprep_kernel<<<dim3(256, 1), 256, 0, stream>>>(p2_wl, wt_p2l, 128, 256, 128);
    wprep_kernel<<<dim3(256, 1), 256, 0, stream>>>(p2_wr, wt_p2r, 128, 256, 128);
    wprep_kernel<<<dim3(512, 1), 256, 0, stream>>>(p3_wl, wt_p3l, 256, 512, 256);
    wprep_kernel<<<dim3(512, 1), 256, 0, stream>>>(p3_wr, wt_p3r, 256, 512, 256);
    wprep_kernel<<<dim3(128, 1), 256, 0, stream>>>(c1_wl, wt_c1l, 78, 128, 96);
    wprep_kernel<<<dim3(128, 1), 256, 0, stream>>>(c1_wr, wt_c1r, 78, 128, 96);
    wprep_kernel<<<dim3(256, 1), 256, 0, stream>>>(c2_wl, wt_c2l, 128, 256, 128);
    wprep_kernel<<<dim3(256, 1), 256, 0, stream>>>(c2_wr, wt_c2r, 128, 256, 128);
    wprep_kernel<<<dim3(512, 1), 256, 0, stream>>>(c3_wl, wt_c3l, 256, 512, 256);
    wprep_kernel<<<dim3(512, 1), 256, 0, stream>>>(c3_wr, wt_c3r, 256, 512, 256);
    cx_conv_kernel<<<(NC_TOT * 96 + 255) / 256, 256, 0, stream>>>(compound_x, cxp);

    // ---- protein CSR ----
    zero_int_kernel<<<(NP_TOT + 255) / 256, 256, 0, stream>>>(p_cursor, NP_TOT);
    hist_kernel<<<(EP_TOT + 255) / 256, 256, 0, stream>>>(prot_tgt, p_cursor, EP_TOT);
    exscan_kernel<<<1, 256, 0, stream>>>(p_cursor, p_rowptr, NP_TOT);
    zero_int_kernel<<<(NP_TOT + 255) / 256, 256, 0, stream>>>(p_cursor, NP_TOT);
    scatter_kernel<<<(EP_TOT + 255) / 256, 256, 0, stream>>>(prot_src, prot_tgt, p_rowptr, p_cursor, p_csr, EP_TOT);
    // ---- compound CSR ----
    zero_int_kernel<<<(NC_TOT + 255) / 256, 256, 0, stream>>>(c_cursor, NC_TOT);
    hist_kernel<<<(EC_TOT + 255) / 256, 256, 0, stream>>>(comp_tgt, c_cursor, EC_TOT);
    exscan_kernel<<<1, 256, 0, stream>>>(c_cursor, c_rowptr, NC_TOT);
    zero_int_kernel<<<(NC_TOT + 255) / 256, 256, 0, stream>>>(c_cursor, NC_TOT);
    scatter_kernel<<<(EC_TOT + 255) / 256, 256, 0, stream>>>(comp_src, comp_tgt, c_rowptr, c_cursor, c_csr, EC_TOT);

    // ---- conv (packed rows) -> pconv [NP,128] f16 ----
    conv_strip_kernel<<<NP_TOT / CVROWS, 256, 0, stream>>>(seq_x, conv_w, conv_b, prot_gather, pconv);

    // ---- compound GNN ----
    agg96_f16_kernel<<<(NC_TOT + 3) / 4, 256, 0, stream>>>(cxp, c_rowptr, c_csr, cagg, NC_TOT);
    gemm_f16_kernel<<<dim3(NC_TOT / 128, 1), 256, 0, stream>>>(
        cagg, wt_c1l, cxp, wt_c1r, c1_bl, cl1, NC_TOT, 96, 128);
    agg128_f16_kernel<<<(NC_TOT + 7) / 8, 256, 0, stream>>>(cl1, c_rowptr, c_csr, cagg, NC_TOT);
    gemm_f16_kernel<<<dim3(NC_TOT / 128, 2), 256, 0, stream>>>(
        cagg, wt_c2l, cl1, wt_c2r, c2_bl, cl2, NC_TOT, 128, 256);
    agg256_f16_kernel<<<(NC_TOT + 3) / 4, 256, 0, stream>>>(cl2, c_rowptr, c_csr, cagg, NC_TOT);
    gemm_f16_kernel<<<dim3(NC_TOT / 128, 4), 256, 0, stream>>>(
        cagg, wt_c3l, cl2, wt_c3r, c3_bl, cl3, NC_TOT, 256, 512);
    pool_comp_kernel<<<dim3(B_GRAPHS, 2), 256, 0, stream>>>(cl3, cpool);

    // ---- protein GNN ----
    agg128_f16_kernel<<<(NP_TOT + 7) / 8, 256, 0, stream>>>(pconv, p_rowptr, p_csr, pagg, NP_TOT);
    gemm_f16_kernel<<<dim3(NP_TOT / 128, 1), 256, 0, stream>>>(
        pagg, wt_p1l, pconv, wt_p1r, p1_bl, pl1, NP_TOT, 128, 128);
    agg128_f16_kernel<<<(NP_TOT + 7) / 8, 256, 0, stream>>>(pl1, p_rowptr, p_csr, pagg, NP_TOT);
    gemm_f16_kernel<<<dim3(NP_TOT / 128, 2), 256, 0, stream>>>(
        pagg, wt_p2l, pl1, wt_p2r, p2_bl, pl2, NP_TOT, 128, 256);
    agg256_f16_kernel<<<(NP_TOT + 3) / 4, 256, 0, stream>>>(pl2, p_rowptr, p_csr, pagg, NP_TOT);
    gemm_f16_kernel<<<dim3(NP_TOT / 128, 4), 256, 0, stream>>>(
        pagg, wt_p3l, pl2, wt_p3r, p3_bl, pl3, NP_TOT, 256, 512);
    pool_prot_partial_kernel<<<dim3(B_GRAPHS, 2, PSPLIT), 256, 0, stream>>>(pl3, ppart);
    pool_prot_final_kernel<<<dim3(B_GRAPHS, 2), 256, 0, stream>>>(ppart, ppool);

    // ---- head ----
    head_kernel<<<B_GRAPHS, 256, 0, stream>>>(cpool, ppool, cfc_w, cfc_b, pfc_w, pfc_b,
                                              fc1_w, fc1_b, out_w, out_b, out);
}

// Round 5
// 555.194 us; speedup vs baseline: 3.5994x; 1.2350x over previous
//
#include <hip/hip_runtime.h>
#include <hip/hip_fp16.h>

// ---------------------------------------------------------------------------
// Problem constants (from reference)
// ---------------------------------------------------------------------------
#define B_GRAPHS 64
#define LMAX 1024
#define NP_TOT 49152      // sum(LENS)
#define NC_TOT 2560       // 64*40
#define EP_TOT 393216     // 8 * NP
#define EC_TOT 10240      // 4 * NC

typedef _Float16 f16x8 __attribute__((ext_vector_type(8)));
typedef _Float16 f16x4 __attribute__((ext_vector_type(4)));
typedef _Float16 f16x2 __attribute__((ext_vector_type(2)));
typedef float    f32x4 __attribute__((ext_vector_type(4)));

__device__ __forceinline__ float lrelu(float x) { return x > 0.f ? x : 0.01f * x; }

// ---------------------------------------------------------------------------
// CSR build (fused, both graphs)
// ---------------------------------------------------------------------------
__global__ void zero_int_kernel(int* p, int n) {
    int i = blockIdx.x * blockDim.x + threadIdx.x;
    if (i < n) p[i] = 0;
}

__global__ void hist2_kernel(const int* __restrict__ ptgt, int* __restrict__ pdeg,
                             const int* __restrict__ ctgt, int* __restrict__ cdeg) {
    int e = blockIdx.x * blockDim.x + threadIdx.x;
    if (e < EP_TOT) atomicAdd(&pdeg[ptgt[e]], 1);
    else if (e < EP_TOT + EC_TOT) atomicAdd(&cdeg[ctgt[e - EP_TOT]], 1);
}

// blockIdx.x == 0 -> protein, == 1 -> compound
__global__ void exscan2_kernel(const int* __restrict__ pin, int* __restrict__ pout,
                               const int* __restrict__ cin, int* __restrict__ cout) {
    __shared__ int part[256];
    const int* in = blockIdx.x ? cin : pin;
    int* out      = blockIdx.x ? cout : pout;
    int n         = blockIdx.x ? NC_TOT : NP_TOT;
    int t = threadIdx.x;
    int chunk = (n + 255) / 256;
    int lo = t * chunk;
    int hi = lo + chunk; if (hi > n) hi = n;
    int s = 0;
    for (int i = lo; i < hi; i++) s += in[i];
    part[t] = s;
    __syncthreads();
    if (t == 0) {
        int run = 0;
        for (int i = 0; i < 256; i++) { int v = part[i]; part[i] = run; run += v; }
    }
    __syncthreads();
    int run = part[t];
    for (int i = lo; i < hi; i++) { out[i] = run; run += in[i]; }
    if (t == 255) out[n] = run;
}

__global__ void scatter2_kernel(const int* __restrict__ ps, const int* __restrict__ pt,
                                const int* __restrict__ prow, int* __restrict__ pcur,
                                int* __restrict__ pcsr,
                                const int* __restrict__ cs, const int* __restrict__ ct,
                                const int* __restrict__ crow, int* __restrict__ ccur,
                                int* __restrict__ ccsr) {
    int e = blockIdx.x * blockDim.x + threadIdx.x;
    if (e < EP_TOT) {
        int t = pt[e];
        int pos = atomicAdd(&pcur[t], 1);
        pcsr[prow[t] + pos] = ps[e];
    } else if (e < EP_TOT + EC_TOT) {
        int e2 = e - EP_TOT;
        int t = ct[e2];
        int pos = atomicAdd(&ccur[t], 1);
        ccsr[crow[t] + pos] = cs[e2];
    }
}

// ---------------------------------------------------------------------------
// fused weight prep: 13 jobs in one launch (blockIdx.z selects)
// mode 0: in f32 [K][D] -> out f16 [D][Kp] (transpose + zero-pad K)
// mode 1: conv weight [128][21][5] -> out f16 [128][128], j = k*21+c
// ---------------------------------------------------------------------------
struct WJob { const float* in; _Float16* out; int K, D, Kp, mode; };
struct WJobs { WJob j[13]; };

__global__ __launch_bounds__(256) void wprep_all_kernel(WJobs jobs) {
    WJob jb = jobs.j[blockIdx.z];
    int idx = blockIdx.x * 256 + threadIdx.x;
    int total = jb.D * jb.Kp;
    if (idx >= total) return;
    float v;
    if (jb.mode == 0) {
        int d = idx / jb.Kp, k = idx - d * jb.Kp;
        v = (k < jb.K) ? jb.in[(long)k * jb.D + d] : 0.f;
    } else {
        int o = idx >> 7, j = idx & 127;
        if (j < 105) {
            int k = j / 21, c = j - k * 21;
            v = jb.in[o * 105 + c * 5 + k];
        } else v = 0.f;
    }
    jb.out[idx] = (_Float16)v;
}

// compound_x f32 [2560][78] -> f16 [2560][96] zero-padded
__global__ void cx_conv_kernel(const float* __restrict__ in, _Float16* __restrict__ out) {
    int i = blockIdx.x * 256 + threadIdx.x;
    if (i >= NC_TOT * 96) return;
    int r = i / 96, k = i - r * 96;
    out[i] = (_Float16)(k < 78 ? in[r * 78 + k] : 0.f);
}

// ---------------------------------------------------------------------------
// im2col for conv1d(k=5, pad=2, Cin=21): row i -> [128] f16, j = k*21+c (pad 105..127)
// ---------------------------------------------------------------------------
__global__ __launch_bounds__(256) void im2col_kernel(
    const float* __restrict__ seq, const int* __restrict__ gather,
    _Float16* __restrict__ out)
{
    int t4 = blockIdx.x * 256 + threadIdx.x;   // one f16x4 group
    int i = t4 >> 5;                           // 32 groups per row
    if (i >= NP_TOT) return;
    int j0 = (t4 & 31) * 4;
    int g = gather[i];
    int bb = g >> 10, l = g & (LMAX - 1);
    f16x4 o;
    #pragma unroll
    for (int u = 0; u < 4; ++u) {
        int j = j0 + u;
        float v = 0.f;
        if (j < 105) {
            int k = j / 21, c = j - k * 21;
            int ll = l + k - 2;
            if ((unsigned)ll < (unsigned)LMAX)
                v = seq[((long)bb * LMAX + ll) * 21 + c];
        }
        o[u] = (_Float16)v;
    }
    *(f16x4*)(out + (long)i * 128 + j0) = o;
}

// ---------------------------------------------------------------------------
// fused dual MFMA GEMM (fp16 in, f32 accum, fp16 out):
//   Out = act(A0 @ W0 [+ A1 @ W1 if npass==2] + bias)
// A: [N][K] f16, WT: [D][K] f16 (pre-transposed), Out: [N][D] f16.
// 128x128 tile, 256 threads = 4 waves (2x2), 4x4 16x16x32 frags per wave.
// LDS chunk-swizzled (c ^= row&3) -> conflict-free b128 read/write.
// Requires: N%128==0, D%128==0, K%32==0.
// ---------------------------------------------------------------------------
__global__ __launch_bounds__(256) void gemm_f16_kernel(
    const _Float16* __restrict__ A0, const _Float16* __restrict__ WT0,
    const _Float16* __restrict__ A1, const _Float16* __restrict__ WT1,
    const float* __restrict__ bias, _Float16* __restrict__ Out,
    int N, int K, int D, int npass, int act)
{
    __shared__ _Float16 Asm[128 * 32];
    __shared__ _Float16 Bsm[128 * 32];
    const int tid = threadIdx.x;
    const int wave = tid >> 6, lane = tid & 63;
    const int wr = wave >> 1, wc = wave & 1;
    const int l15 = lane & 15, lk = lane >> 4;
    const long r0 = (long)blockIdx.x * 128;
    const long c0 = (long)blockIdx.y * 128;

    // staging assignment: thread -> (row srow, 16B chunk sc), rows srow & srow+64
    const int srow = tid >> 2, sc = tid & 3;
    const int w0 = srow * 32 + ((sc ^ (srow & 3)) * 8);
    const int w1 = w0 + 64 * 32;      // (srow+64)&3 == srow&3

    // fragment read offsets (constant across K-steps)
    int aoff[4], boff[4];
    #pragma unroll
    for (int m = 0; m < 4; ++m) {
        int row = wr * 64 + m * 16 + l15;
        aoff[m] = row * 32 + ((lk ^ (row & 3)) * 8);
        int col = wc * 64 + m * 16 + l15;
        boff[m] = col * 32 + ((lk ^ (col & 3)) * 8);
    }

    f32x4 acc[4][4];
    #pragma unroll
    for (int m = 0; m < 4; ++m)
        #pragma unroll
        for (int n = 0; n < 4; ++n)
            #pragma unroll
            for (int i = 0; i < 4; ++i) acc[m][n][i] = 0.f;

    const int ksteps = K >> 5;
    const int S = ksteps * npass;

    // prologue: load step 0 (pass 0, k0 = 0)
    f16x8 av0, av1, bv0, bv1;
    {
        const long kb = sc * 8;
        av0 = *(const f16x8*)(A0  + (r0 + srow) * K + kb);
        av1 = *(const f16x8*)(A0  + (r0 + srow + 64) * K + kb);
        bv0 = *(const f16x8*)(WT0 + (c0 + srow) * K + kb);
        bv1 = *(const f16x8*)(WT0 + (c0 + srow + 64) * K + kb);
    }

    for (int s = 0; s < S; ++s) {
        __syncthreads();                      // LDS free (prev compute done)
        *(f16x8*)(Asm + w0) = av0;
        *(f16x8*)(Asm + w1) = av1;
        *(f16x8*)(Bsm + w0) = bv0;
        *(f16x8*)(Bsm + w1) = bv1;
        __syncthreads();                      // tile ready
        if (s + 1 < S) {                      // prefetch next tile (overlaps MFMA)
            int s1 = s + 1;
            int pass = (s1 >= ksteps) ? 1 : 0;
            long kb = (long)(s1 - pass * ksteps) * 32 + sc * 8;
            const _Float16* Ax = pass ? A1 : A0;
            const _Float16* Wx = pass ? WT1 : WT0;
            av0 = *(const f16x8*)(Ax + (r0 + srow) * K + kb);
            av1 = *(const f16x8*)(Ax + (r0 + srow + 64) * K + kb);
            bv0 = *(const f16x8*)(Wx + (c0 + srow) * K + kb);
            bv1 = *(const f16x8*)(Wx + (c0 + srow + 64) * K + kb);
        }
        f16x8 af[4], bf[4];
        #pragma unroll
        for (int m = 0; m < 4; ++m) af[m] = *(const f16x8*)(Asm + aoff[m]);
        #pragma unroll
        for (int n = 0; n < 4; ++n) bf[n] = *(const f16x8*)(Bsm + boff[n]);
        #pragma unroll
        for (int m = 0; m < 4; ++m)
            #pragma unroll
            for (int n = 0; n < 4; ++n)
                acc[m][n] = __builtin_amdgcn_mfma_f32_16x16x32_f16(af[m], bf[n], acc[m][n], 0, 0, 0);
    }

    // epilogue: bias + act + fp16 store
    float bn[4]; int coln[4];
    #pragma unroll
    for (int n = 0; n < 4; ++n) {
        coln[n] = (int)c0 + wc * 64 + n * 16 + l15;
        bn[n] = bias[coln[n]];
    }
    #pragma unroll
    for (int m = 0; m < 4; ++m) {
        long rowb = r0 + wr * 64 + m * 16 + lk * 4;
        #pragma unroll
        for (int i = 0; i < 4; ++i) {
            long row = rowb + i;
            #pragma unroll
            for (int n = 0; n < 4; ++n) {
                float v = acc[m][n][i] + bn[n];
                if (act) v = v > 0.f ? v : 0.01f * v;
                Out[row * D + coln[n]] = (_Float16)v;
            }
        }
    }
}

// ---------------------------------------------------------------------------
// CSR aggregation, fp16 in/out, f32 accumulate
// ---------------------------------------------------------------------------
__global__ __launch_bounds__(256) void agg256_f16_kernel(
    const _Float16* __restrict__ x, const int* __restrict__ rowptr,
    const int* __restrict__ csr, _Float16* __restrict__ agg, int n)
{
    int node = (blockIdx.x * 256 + threadIdx.x) >> 6;
    int lane = threadIdx.x & 63;
    if (node >= n) return;
    int beg = rowptr[node], end = rowptr[node + 1];
    float a0 = 0.f, a1 = 0.f, a2 = 0.f, a3 = 0.f;
    for (int j = beg; j < end; ++j) {
        int s = csr[j];
        f16x4 v = *(const f16x4*)(x + (long)s * 256 + lane * 4);
        a0 += (float)v[0]; a1 += (float)v[1]; a2 += (float)v[2]; a3 += (float)v[3];
    }
    f16x4 o; o[0] = (_Float16)a0; o[1] = (_Float16)a1; o[2] = (_Float16)a2; o[3] = (_Float16)a3;
    *(f16x4*)(agg + (long)node * 256 + lane * 4) = o;
}

__global__ __launch_bounds__(256) void agg128_f16_kernel(
    const _Float16* __restrict__ x, const int* __restrict__ rowptr,
    const int* __restrict__ csr, _Float16* __restrict__ agg, int n)
{
    int node = (blockIdx.x * 256 + threadIdx.x) >> 5;
    int lane = threadIdx.x & 31;
    if (node >= n) return;
    int beg = rowptr[node], end = rowptr[node + 1];
    float a0 = 0.f, a1 = 0.f, a2 = 0.f, a3 = 0.f;
    for (int j = beg; j < end; ++j) {
        int s = csr[j];
        f16x4 v = *(const f16x4*)(x + (long)s * 128 + lane * 4);
        a0 += (float)v[0]; a1 += (float)v[1]; a2 += (float)v[2]; a3 += (float)v[3];
    }
    f16x4 o; o[0] = (_Float16)a0; o[1] = (_Float16)a1; o[2] = (_Float16)a2; o[3] = (_Float16)a3;
    *(f16x4*)(agg + (long)node * 128 + lane * 4) = o;
}

__global__ __launch_bounds__(256) void agg96_f16_kernel(
    const _Float16* __restrict__ x, const int* __restrict__ rowptr,
    const int* __restrict__ csr, _Float16* __restrict__ agg, int n)
{
    int node = (blockIdx.x * 256 + threadIdx.x) >> 6;
    int lane = threadIdx.x & 63;
    if (node >= n) return;
    if (lane < 48) {
        int beg = rowptr[node], end = rowptr[node + 1];
        float a0 = 0.f, a1 = 0.f;
        for (int j = beg; j < end; ++j) {
            int s = csr[j];
            f16x2 v = *(const f16x2*)(x + (long)s * 96 + lane * 2);
            a0 += (float)v[0]; a1 += (float)v[1];
        }
        f16x2 o; o[0] = (_Float16)a0; o[1] = (_Float16)a1;
        *(f16x2*)(agg + (long)node * 96 + lane * 2) = o;
    }
}

// ---------------------------------------------------------------------------
// pooling (fp16 input, f32 output)
// ---------------------------------------------------------------------------
__global__ __launch_bounds__(256) void pool_comp_kernel(
    const _Float16* __restrict__ x, float* __restrict__ out)
{
    int g = blockIdx.x;
    int c = blockIdx.y * 256 + threadIdx.x;
    float m = -INFINITY;
    for (int r = 0; r < 40; ++r)
        m = fmaxf(m, (float)x[(long)(g * 40 + r) * 512 + c]);
    out[g * 512 + c] = m;
}

#define PSPLIT 4
__global__ __launch_bounds__(256) void pool_prot_partial_kernel(
    const _Float16* __restrict__ x, float* __restrict__ part)
{
    int g = blockIdx.x, cb = blockIdx.y, s = blockIdx.z;
    int col = cb * 256 + threadIdx.x;
    int start = 512 * ((g + 1) / 2) + 1024 * (g / 2);
    int len = (g & 1) ? 1024 : 512;
    int chunk = len / PSPLIT;
    int r0 = s * chunk;
    float m = -INFINITY;
    #pragma unroll 4
    for (int r = 0; r < chunk; ++r)
        m = fmaxf(m, (float)x[(long)(start + r0 + r) * 512 + col]);
    part[(long)(g * PSPLIT + s) * 512 + col] = m;
}

__global__ __launch_bounds__(256) void pool_prot_final_kernel(
    const float* __restrict__ part, float* __restrict__ out)
{
    int g = blockIdx.x;
    int col = blockIdx.y * 256 + threadIdx.x;
    float m = -INFINITY;
    #pragma unroll
    for (int s = 0; s < PSPLIT; ++s)
        m = fmaxf(m, part[(long)(g * PSPLIT + s) * 512 + col]);
    out[g * 512 + col] = m;
}

// ---------------------------------------------------------------------------
// head: cfc/pfc -> concat -> fc1 -> out   (one block per graph, f32)
// ---------------------------------------------------------------------------
__global__ __launch_bounds__(256) void head_kernel(
    const float* __restrict__ cpool, const float* __restrict__ ppool,
    const float* __restrict__ cfc_w, const float* __restrict__ cfc_b,
    const float* __restrict__ pfc_w, const float* __restrict__ pfc_b,
    const float* __restrict__ fc1_w, const float* __restrict__ fc1_b,
    const float* __restrict__ out_w, const float* __restrict__ out_b,
    float* __restrict__ out)
{
    __shared__ float cp[512], pp[512], cf[128], pf[128], h[256], red[256];
    int g = blockIdx.x, t = threadIdx.x;
    for (int i = t; i < 512; i += 256) {
        cp[i] = cpool[g * 512 + i];
        pp[i] = ppool[g * 512 + i];
    }
    __syncthreads();
    if (t < 128) {
        float a = cfc_b[t];
        for (int k = 0; k < 512; k++) a += cp[k] * cfc_w[k * 128 + t];
        cf[t] = lrelu(a);
    } else {
        int o = t - 128;
        float a = pfc_b[o];
        for (int k = 0; k < 512; k++) a += pp[k] * pfc_w[k * 128 + o];
        pf[o] = lrelu(a);
    }
    __syncthreads();
    {
        float a = fc1_b[t];
        for (int k = 0; k < 128; k++) a += cf[k] * fc1_w[k * 256 + t];
        for (int k = 0; k < 128; k++) a += pf[k] * fc1_w[(128 + k) * 256 + t];
        h[t] = lrelu(a);
    }
    __syncthreads();
    red[t] = h[t] * out_w[t];
    __syncthreads();
    for (int s = 128; s > 0; s >>= 1) {
        if (t < s) red[t] += red[t + s];
        __syncthreads();
    }
    if (t == 0) out[g] = red[0] + out_b[0];
}

// ---------------------------------------------------------------------------
// launch
// ---------------------------------------------------------------------------
extern "C" void kernel_launch(void* const* d_in, const int* in_sizes, int n_in,
                              void* d_out, int out_size, void* d_ws, size_t ws_size,
                              hipStream_t stream) {
    const float* seq_x      = (const float*)d_in[0];
    const float* compound_x = (const float*)d_in[1];
    const float* conv_w     = (const float*)d_in[2];
    const float* conv_b     = (const float*)d_in[3];
    const float* c1_wl = (const float*)d_in[4];
    const float* c1_bl = (const float*)d_in[5];
    const float* c1_wr = (const float*)d_in[6];
    const float* c2_wl = (const float*)d_in[7];
    const float* c2_bl = (const float*)d_in[8];
    const float* c2_wr = (const float*)d_in[9];
    const float* c3_wl = (const float*)d_in[10];
    const float* c3_bl = (const float*)d_in[11];
    const float* c3_wr = (const float*)d_in[12];
    const float* cfc_w = (const float*)d_in[13];
    const float* cfc_b = (const float*)d_in[14];
    const float* p1_wl = (const float*)d_in[15];
    const float* p1_bl = (const float*)d_in[16];
    const float* p1_wr = (const float*)d_in[17];
    const float* p2_wl = (const float*)d_in[18];
    const float* p2_bl = (const float*)d_in[19];
    const float* p2_wr = (const float*)d_in[20];
    const float* p3_wl = (const float*)d_in[21];
    const float* p3_bl = (const float*)d_in[22];
    const float* p3_wr = (const float*)d_in[23];
    const float* pfc_w = (const float*)d_in[24];
    const float* pfc_b = (const float*)d_in[25];
    const float* fc1_w = (const float*)d_in[26];
    const float* fc1_b = (const float*)d_in[27];
    const float* out_w = (const float*)d_in[28];
    const float* out_b = (const float*)d_in[29];
    const int* prot_gather = (const int*)d_in[30];
    const int* prot_src    = (const int*)d_in[31];
    const int* prot_tgt    = (const int*)d_in[32];
    const int* comp_src    = (const int*)d_in[33];
    const int* comp_tgt    = (const int*)d_in[34];

    float* out = (float*)d_out;

    // workspace layout
    size_t off = 0;
    auto alloc = [&](size_t bytes) -> char* {
        char* p = (char*)d_ws + off;
        off = (off + bytes + 255) & ~(size_t)255;
        return p;
    };
    // fp16 activation buffers
    _Float16* pim   = (_Float16*)alloc((size_t)NP_TOT * 128 * 2);   // im2col
    _Float16* pconv = (_Float16*)alloc((size_t)NP_TOT * 128 * 2);
    _Float16* pagg  = (_Float16*)alloc((size_t)NP_TOT * 256 * 2);
    _Float16* pl1   = (_Float16*)alloc((size_t)NP_TOT * 128 * 2);
    _Float16* pl2   = (_Float16*)alloc((size_t)NP_TOT * 256 * 2);
    _Float16* pl3   = (_Float16*)alloc((size_t)NP_TOT * 512 * 2);
    _Float16* cxp   = (_Float16*)alloc((size_t)NC_TOT * 96 * 2);
    _Float16* cagg  = (_Float16*)alloc((size_t)NC_TOT * 256 * 2);
    _Float16* cl1   = (_Float16*)alloc((size_t)NC_TOT * 128 * 2);
    _Float16* cl2   = (_Float16*)alloc((size_t)NC_TOT * 256 * 2);
    _Float16* cl3   = (_Float16*)alloc((size_t)NC_TOT * 512 * 2);
    // fp16 transposed weights [D][Kp]
    _Float16* wt_p1l = (_Float16*)alloc(128 * 128 * 2);
    _Float16* wt_p1r = (_Float16*)alloc(128 * 128 * 2);
    _Float16* wt_p2l = (_Float16*)alloc(256 * 128 * 2);
    _Float16* wt_p2r = (_Float16*)alloc(256 * 128 * 2);
    _Float16* wt_p3l = (_Float16*)alloc(512 * 256 * 2);
    _Float16* wt_p3r = (_Float16*)alloc(512 * 256 * 2);
    _Float16* wt_c1l = (_Float16*)alloc(128 * 96 * 2);
    _Float16* wt_c1r = (_Float16*)alloc(128 * 96 * 2);
    _Float16* wt_c2l = (_Float16*)alloc(256 * 128 * 2);
    _Float16* wt_c2r = (_Float16*)alloc(256 * 128 * 2);
    _Float16* wt_c3l = (_Float16*)alloc(512 * 256 * 2);
    _Float16* wt_c3r = (_Float16*)alloc(512 * 256 * 2);
    _Float16* wt_cv  = (_Float16*)alloc(128 * 128 * 2);
    // pools (f32)
    float* cpool = (float*)alloc(B_GRAPHS * 512 * 4);
    float* ppool = (float*)alloc(B_GRAPHS * 512 * 4);
    float* ppart = (float*)alloc((size_t)B_GRAPHS * PSPLIT * 512 * 4);
    // CSR (cursors contiguous so one zero pass covers both)
    int* cursors  = (int*)alloc((NP_TOT + NC_TOT) * 4);
    int* p_cursor = cursors;
    int* c_cursor = cursors + NP_TOT;
    int* p_rowptr = (int*)alloc((NP_TOT + 1) * 4);
    int* p_csr    = (int*)alloc(EP_TOT * 4);
    int* c_rowptr = (int*)alloc((NC_TOT + 1) * 4);
    int* c_csr    = (int*)alloc(EC_TOT * 4);
    (void)ws_size; (void)n_in; (void)in_sizes; (void)out_size;

    // ---- weight prep (one launch) + compound input conversion ----
    WJobs jobs;
    jobs.j[0]  = { p1_wl, wt_p1l, 128, 128, 128, 0 };
    jobs.j[1]  = { p1_wr, wt_p1r, 128, 128, 128, 0 };
    jobs.j[2]  = { p2_wl, wt_p2l, 128, 256, 128, 0 };
    jobs.j[3]  = { p2_wr, wt_p2r, 128, 256, 128, 0 };
    jobs.j[4]  = { p3_wl, wt_p3l, 256, 512, 256, 0 };
    jobs.j[5]  = { p3_wr, wt_p3r, 256, 512, 256, 0 };
    jobs.j[6]  = { c1_wl, wt_c1l,  78, 128,  96, 0 };
    jobs.j[7]  = { c1_wr, wt_c1r,  78, 128,  96, 0 };
    jobs.j[8]  = { c2_wl, wt_c2l, 128, 256, 128, 0 };
    jobs.j[9]  = { c2_wr, wt_c2r, 128, 256, 128, 0 };
    jobs.j[10] = { c3_wl, wt_c3l, 256, 512, 256, 0 };
    jobs.j[11] = { c3_wr, wt_c3r, 256, 512, 256, 0 };
    jobs.j[12] = { conv_w, wt_cv, 105, 128, 128, 1 };
    wprep_all_kernel<<<dim3(512, 1, 13), 256, 0, stream>>>(jobs);
    cx_conv_kernel<<<(NC_TOT * 96 + 255) / 256, 256, 0, stream>>>(compound_x, cxp);

    // ---- CSR build (both graphs, fused) ----
    zero_int_kernel<<<(NP_TOT + NC_TOT + 255) / 256, 256, 0, stream>>>(cursors, NP_TOT + NC_TOT);
    hist2_kernel<<<(EP_TOT + EC_TOT + 255) / 256, 256, 0, stream>>>(prot_tgt, p_cursor, comp_tgt, c_cursor);
    exscan2_kernel<<<2, 256, 0, stream>>>(p_cursor, p_rowptr, c_cursor, c_rowptr);
    zero_int_kernel<<<(NP_TOT + NC_TOT + 255) / 256, 256, 0, stream>>>(cursors, NP_TOT + NC_TOT);
    scatter2_kernel<<<(EP_TOT + EC_TOT + 255) / 256, 256, 0, stream>>>(
        prot_src, prot_tgt, p_rowptr, p_cursor, p_csr,
        comp_src, comp_tgt, c_rowptr, c_cursor, c_csr);

    // ---- conv as im2col + MFMA GEMM -> pconv [NP,128] f16 (no activation) ----
    im2col_kernel<<<(NP_TOT * 32 + 255) / 256, 256, 0, stream>>>(seq_x, prot_gather, pim);
    gemm_f16_kernel<<<dim3(NP_TOT / 128, 1), 256, 0, stream>>>(
        pim, wt_cv, pim, wt_cv, conv_b, pconv, NP_TOT, 128, 128, 1, 0);

    // ---- compound GNN ----
    agg96_f16_kernel<<<(NC_TOT + 3) / 4, 256, 0, stream>>>(cxp, c_rowptr, c_csr, cagg, NC_TOT);
    gemm_f16_kernel<<<dim3(NC_TOT / 128, 1), 256, 0, stream>>>(
        cagg, wt_c1l, cxp, wt_c1r, c1_bl, cl1, NC_TOT, 96, 128, 2, 1);
    agg128_f16_kernel<<<(NC_TOT + 7) / 8, 256, 0, stream>>>(cl1, c_rowptr, c_csr, cagg, NC_TOT);
    gemm_f16_kernel<<<dim3(NC_TOT / 128, 2), 256, 0, stream>>>(
        cagg, wt_c2l, cl1, wt_c2r, c2_bl, cl2, NC_TOT, 128, 256, 2, 1);
    agg256_f16_kernel<<<(NC_TOT + 3) / 4, 256, 0, stream>>>(cl2, c_rowptr, c_csr, cagg, NC_TOT);
    gemm_f16_kernel<<<dim3(NC_TOT / 128, 4), 256, 0, stream>>>(
        cagg, wt_c3l, cl2, wt_c3r, c3_bl, cl3, NC_TOT, 256, 512, 2, 1);
    pool_comp_kernel<<<dim3(B_GRAPHS, 2), 256, 0, stream>>>(cl3, cpool);

    // ---- protein GNN ----
    agg128_f16_kernel<<<(NP_TOT + 7) / 8, 256, 0, stream>>>(pconv, p_rowptr, p_csr, pagg, NP_TOT);
    gemm_f16_kernel<<<dim3(NP_TOT / 128, 1), 256, 0, stream>>>(
        pagg, wt_p1l, pconv, wt_p1r, p1_bl, pl1, NP_TOT, 128, 128, 2, 1);
    agg128_f16_kernel<<<(NP_TOT + 7) / 8, 256, 0, stream>>>(pl1, p_rowptr, p_csr, pagg, NP_TOT);
    gemm_f16_kernel<<<dim3(NP_TOT / 128, 2), 256, 0, stream>>>(
        pagg, wt_p2l, pl1, wt_p2r, p2_bl, pl2, NP_TOT, 128, 256, 2, 1);
    agg256_f16_kernel<<<(NP_TOT + 3) / 4, 256, 0, stream>>>(pl2, p_rowptr, p_csr, pagg, NP_TOT);
    gemm_f16_kernel<<<dim3(NP_TOT / 128, 4), 256, 0, stream>>>(
        pagg, wt_p3l, pl2, wt_p3r, p3_bl, pl3, NP_TOT, 256, 512, 2, 1);
    pool_prot_partial_kernel<<<dim3(B_GRAPHS, 2, PSPLIT), 256, 0, stream>>>(pl3, ppart);
    pool_prot_final_kernel<<<dim3(B_GRAPHS, 2), 256, 0, stream>>>(ppart, ppool);

    // ---- head ----
    head_kernel<<<B_GRAPHS, 256, 0, stream>>>(cpool, ppool, cfc_w, cfc_b, pfc_w, pfc_b,
                                              fc1_w, fc1_b, out_w, out_b, out);
}

// Round 6
// 484.428 us; speedup vs baseline: 4.1252x; 1.1461x over previous
//
#include <hip/hip_runtime.h>
#include <hip/hip_fp16.h>

// ---------------------------------------------------------------------------
// Problem constants (from reference)
// ---------------------------------------------------------------------------
#define B_GRAPHS 64
#define LMAX 1024
#define NP_TOT 49152      // sum(LENS)
#define NC_TOT 2560       // 64*40
#define EP_TOT 393216     // 8 * NP
#define EC_TOT 10240      // 4 * NC

#define SCAN_N   (NP_TOT + NC_TOT)   // 51712
#define SCAN_BLK 512
#define SCAN_NB  (SCAN_N / SCAN_BLK) // 101 (exact)

typedef _Float16 f16x8 __attribute__((ext_vector_type(8)));
typedef _Float16 f16x4 __attribute__((ext_vector_type(4)));
typedef _Float16 f16x2 __attribute__((ext_vector_type(2)));
typedef float    f32x4 __attribute__((ext_vector_type(4)));

__device__ __forceinline__ float lrelu(float x) { return x > 0.f ? x : 0.01f * x; }

// ---------------------------------------------------------------------------
// CSR build (fused, both graphs)
// ---------------------------------------------------------------------------
__global__ void zero_int_kernel(int* p, int n) {
    int i = blockIdx.x * blockDim.x + threadIdx.x;
    if (i < n) p[i] = 0;
}

__global__ void hist2_kernel(const int* __restrict__ ptgt, int* __restrict__ pdeg,
                             const int* __restrict__ ctgt, int* __restrict__ cdeg) {
    int e = blockIdx.x * blockDim.x + threadIdx.x;
    if (e < EP_TOT) atomicAdd(&pdeg[ptgt[e]], 1);
    else if (e < EP_TOT + EC_TOT) atomicAdd(&cdeg[ctgt[e - EP_TOT]], 1);
}

// ---- parallel exclusive scan over the concatenated degree array ----
// phase 1: per-block (512 elems) sums
__global__ __launch_bounds__(256) void scan_bsum_kernel(
    const int* __restrict__ deg, int* __restrict__ bsums)
{
    __shared__ int red[256];
    int b = blockIdx.x, t = threadIdx.x;
    int2 e = *(const int2*)(deg + b * SCAN_BLK + t * 2);
    red[t] = e.x + e.y;
    __syncthreads();
    for (int s = 128; s > 0; s >>= 1) {
        if (t < s) red[t] += red[t + s];
        __syncthreads();
    }
    if (t == 0) bsums[b] = red[0];
}

// phase 2: single-block exclusive scan of the SCAN_NB block sums (in place)
__global__ __launch_bounds__(128) void scan_sums_kernel(int* __restrict__ bsums)
{
    __shared__ int v[SCAN_NB];
    int t = threadIdx.x;
    if (t < SCAN_NB) v[t] = bsums[t];
    __syncthreads();
    if (t == 0) {
        int run = 0;
        for (int i = 0; i < SCAN_NB; ++i) { int x = v[i]; v[i] = run; run += x; }
    }
    __syncthreads();
    if (t < SCAN_NB) bsums[t] = v[t];
}

// phase 3: intra-block exclusive scan + block offset -> rowptrs.
// scan[NP_TOT] == EP_TOT exactly, so c_rowptr[i] = scan[NP_TOT+i] - EP_TOT.
__global__ __launch_bounds__(256) void scan_final_kernel(
    const int* __restrict__ deg, const int* __restrict__ bsums,
    int* __restrict__ p_rowptr, int* __restrict__ c_rowptr)
{
    __shared__ int wsum[4];
    int b = blockIdx.x, t = threadIdx.x;
    int i = b * SCAN_BLK + t * 2;
    int2 e = *(const int2*)(deg + i);
    int ts = e.x + e.y;
    int lane = t & 63, wv = t >> 6;
    int x = ts;
    #pragma unroll
    for (int o = 1; o < 64; o <<= 1) {
        int y = __shfl_up(x, o);
        if (lane >= o) x += y;
    }
    if (lane == 63) wsum[wv] = x;
    __syncthreads();
    int base = bsums[b];
    for (int w = 0; w < wv; ++w) base += wsum[w];
    int excl = base + x - ts;
    int v0 = excl, v1 = excl + e.x;
    if (i < NP_TOT) p_rowptr[i] = v0; else c_rowptr[i - NP_TOT] = v0 - EP_TOT;
    if (i + 1 < NP_TOT) p_rowptr[i + 1] = v1; else c_rowptr[i + 1 - NP_TOT] = v1 - EP_TOT;
    if (b == 0 && t == 0) { p_rowptr[NP_TOT] = EP_TOT; c_rowptr[NC_TOT] = EC_TOT; }
}

__global__ void scatter2_kernel(const int* __restrict__ ps, const int* __restrict__ pt,
                                const int* __restrict__ prow, int* __restrict__ pcur,
                                int* __restrict__ pcsr,
                                const int* __restrict__ cs, const int* __restrict__ ct,
                                const int* __restrict__ crow, int* __restrict__ ccur,
                                int* __restrict__ ccsr) {
    int e = blockIdx.x * blockDim.x + threadIdx.x;
    if (e < EP_TOT) {
        int t = pt[e];
        int pos = atomicAdd(&pcur[t], 1);
        pcsr[prow[t] + pos] = ps[e];
    } else if (e < EP_TOT + EC_TOT) {
        int e2 = e - EP_TOT;
        int t = ct[e2];
        int pos = atomicAdd(&ccur[t], 1);
        ccsr[crow[t] + pos] = cs[e2];
    }
}

// ---------------------------------------------------------------------------
// fused weight prep: 13 jobs in one launch (blockIdx.z selects)
// mode 0: in f32 [K][D] -> out f16 [D][Kp] (transpose + zero-pad K)
// mode 1: conv weight [128][21][5] -> out f16 [128][128], j = k*21+c
// ---------------------------------------------------------------------------
struct WJob { const float* in; _Float16* out; int K, D, Kp, mode; };
struct WJobs { WJob j[13]; };

__global__ __launch_bounds__(256) void wprep_all_kernel(WJobs jobs) {
    WJob jb = jobs.j[blockIdx.z];
    int idx = blockIdx.x * 256 + threadIdx.x;
    int total = jb.D * jb.Kp;
    if (idx >= total) return;
    float v;
    if (jb.mode == 0) {
        int d = idx / jb.Kp, k = idx - d * jb.Kp;
        v = (k < jb.K) ? jb.in[(long)k * jb.D + d] : 0.f;
    } else {
        int o = idx >> 7, j = idx & 127;
        if (j < 105) {
            int k = j / 21, c = j - k * 21;
            v = jb.in[o * 105 + c * 5 + k];
        } else v = 0.f;
    }
    jb.out[idx] = (_Float16)v;
}

// compound_x f32 [2560][78] -> f16 [2560][96] zero-padded
__global__ void cx_conv_kernel(const float* __restrict__ in, _Float16* __restrict__ out) {
    int i = blockIdx.x * 256 + threadIdx.x;
    if (i >= NC_TOT * 96) return;
    int r = i / 96, k = i - r * 96;
    out[i] = (_Float16)(k < 78 ? in[r * 78 + k] : 0.f);
}

// ---------------------------------------------------------------------------
// im2col for conv1d(k=5, pad=2, Cin=21): row i -> [128] f16, j = k*21+c (pad 105..127)
// ---------------------------------------------------------------------------
__global__ __launch_bounds__(256) void im2col_kernel(
    const float* __restrict__ seq, const int* __restrict__ gather,
    _Float16* __restrict__ out)
{
    int t4 = blockIdx.x * 256 + threadIdx.x;   // one f16x4 group
    int i = t4 >> 5;                           // 32 groups per row
    if (i >= NP_TOT) return;
    int j0 = (t4 & 31) * 4;
    int g = gather[i];
    int bb = g >> 10, l = g & (LMAX - 1);
    f16x4 o;
    #pragma unroll
    for (int u = 0; u < 4; ++u) {
        int j = j0 + u;
        float v = 0.f;
        if (j < 105) {
            int k = j / 21, c = j - k * 21;
            int ll = l + k - 2;
            if ((unsigned)ll < (unsigned)LMAX)
                v = seq[((long)bb * LMAX + ll) * 21 + c];
        }
        o[u] = (_Float16)v;
    }
    *(f16x4*)(out + (long)i * 128 + j0) = o;
}

// ---------------------------------------------------------------------------
// fused dual MFMA GEMM (fp16 in, f32 accum, fp16 out):
//   Out = act(A0 @ W0 [+ A1 @ W1 if npass==2] + bias)
// A: [N][K] f16, WT: [D][K] f16 (pre-transposed), Out: [N][D] f16.
// 128x128 tile, 256 threads = 4 waves (2x2), 4x4 16x16x32 frags per wave.
// LDS chunk-swizzled (c ^= row&3) -> conflict-free b128 read/write.
// Requires: N%128==0, D%128==0, K%32==0.
// ---------------------------------------------------------------------------
__global__ __launch_bounds__(256) void gemm_f16_kernel(
    const _Float16* __restrict__ A0, const _Float16* __restrict__ WT0,
    const _Float16* __restrict__ A1, const _Float16* __restrict__ WT1,
    const float* __restrict__ bias, _Float16* __restrict__ Out,
    int N, int K, int D, int npass, int act)
{
    __shared__ _Float16 Asm[128 * 32];
    __shared__ _Float16 Bsm[128 * 32];
    const int tid = threadIdx.x;
    const int wave = tid >> 6, lane = tid & 63;
    const int wr = wave >> 1, wc = wave & 1;
    const int l15 = lane & 15, lk = lane >> 4;
    const long r0 = (long)blockIdx.x * 128;
    const long c0 = (long)blockIdx.y * 128;

    // staging assignment: thread -> (row srow, 16B chunk sc), rows srow & srow+64
    const int srow = tid >> 2, sc = tid & 3;
    const int w0 = srow * 32 + ((sc ^ (srow & 3)) * 8);
    const int w1 = w0 + 64 * 32;      // (srow+64)&3 == srow&3

    // fragment read offsets (constant across K-steps)
    int aoff[4], boff[4];
    #pragma unroll
    for (int m = 0; m < 4; ++m) {
        int row = wr * 64 + m * 16 + l15;
        aoff[m] = row * 32 + ((lk ^ (row & 3)) * 8);
        int col = wc * 64 + m * 16 + l15;
        boff[m] = col * 32 + ((lk ^ (col & 3)) * 8);
    }

    f32x4 acc[4][4];
    #pragma unroll
    for (int m = 0; m < 4; ++m)
        #pragma unroll
        for (int n = 0; n < 4; ++n)
            #pragma unroll
            for (int i = 0; i < 4; ++i) acc[m][n][i] = 0.f;

    const int ksteps = K >> 5;
    const int S = ksteps * npass;

    // prologue: load step 0 (pass 0, k0 = 0)
    f16x8 av0, av1, bv0, bv1;
    {
        const long kb = sc * 8;
        av0 = *(const f16x8*)(A0  + (r0 + srow) * K + kb);
        av1 = *(const f16x8*)(A0  + (r0 + srow + 64) * K + kb);
        bv0 = *(const f16x8*)(WT0 + (c0 + srow) * K + kb);
        bv1 = *(const f16x8*)(WT0 + (c0 + srow + 64) * K + kb);
    }

    for (int s = 0; s < S; ++s) {
        __syncthreads();                      // LDS free (prev compute done)
        *(f16x8*)(Asm + w0) = av0;
        *(f16x8*)(Asm + w1) = av1;
        *(f16x8*)(Bsm + w0) = bv0;
        *(f16x8*)(Bsm + w1) = bv1;
        __syncthreads();                      // tile ready
        if (s + 1 < S) {                      // prefetch next tile (overlaps MFMA)
            int s1 = s + 1;
            int pass = (s1 >= ksteps) ? 1 : 0;
            long kb = (long)(s1 - pass * ksteps) * 32 + sc * 8;
            const _Float16* Ax = pass ? A1 : A0;
            const _Float16* Wx = pass ? WT1 : WT0;
            av0 = *(const f16x8*)(Ax + (r0 + srow) * K + kb);
            av1 = *(const f16x8*)(Ax + (r0 + srow + 64) * K + kb);
            bv0 = *(const f16x8*)(Wx + (c0 + srow) * K + kb);
            bv1 = *(const f16x8*)(Wx + (c0 + srow + 64) * K + kb);
        }
        f16x8 af[4], bf[4];
        #pragma unroll
        for (int m = 0; m < 4; ++m) af[m] = *(const f16x8*)(Asm + aoff[m]);
        #pragma unroll
        for (int n = 0; n < 4; ++n) bf[n] = *(const f16x8*)(Bsm + boff[n]);
        #pragma unroll
        for (int m = 0; m < 4; ++m)
            #pragma unroll
            for (int n = 0; n < 4; ++n)
                acc[m][n] = __builtin_amdgcn_mfma_f32_16x16x32_f16(af[m], bf[n], acc[m][n], 0, 0, 0);
    }

    // epilogue: bias + act + fp16 store
    float bn[4]; int coln[4];
    #pragma unroll
    for (int n = 0; n < 4; ++n) {
        coln[n] = (int)c0 + wc * 64 + n * 16 + l15;
        bn[n] = bias[coln[n]];
    }
    #pragma unroll
    for (int m = 0; m < 4; ++m) {
        long rowb = r0 + wr * 64 + m * 16 + lk * 4;
        #pragma unroll
        for (int i = 0; i < 4; ++i) {
            long row = rowb + i;
            #pragma unroll
            for (int n = 0; n < 4; ++n) {
                float v = acc[m][n][i] + bn[n];
                if (act) v = v > 0.f ? v : 0.01f * v;
                Out[row * D + coln[n]] = (_Float16)v;
            }
        }
    }
}

// ---------------------------------------------------------------------------
// CSR aggregation, fp16 in/out, f32 accumulate
// ---------------------------------------------------------------------------
__global__ __launch_bounds__(256) void agg256_f16_kernel(
    const _Float16* __restrict__ x, const int* __restrict__ rowptr,
    const int* __restrict__ csr, _Float16* __restrict__ agg, int n)
{
    int node = (blockIdx.x * 256 + threadIdx.x) >> 6;
    int lane = threadIdx.x & 63;
    if (node >= n) return;
    int beg = rowptr[node], end = rowptr[node + 1];
    float a0 = 0.f, a1 = 0.f, a2 = 0.f, a3 = 0.f;
    for (int j = beg; j < end; ++j) {
        int s = csr[j];
        f16x4 v = *(const f16x4*)(x + (long)s * 256 + lane * 4);
        a0 += (float)v[0]; a1 += (float)v[1]; a2 += (float)v[2]; a3 += (float)v[3];
    }
    f16x4 o; o[0] = (_Float16)a0; o[1] = (_Float16)a1; o[2] = (_Float16)a2; o[3] = (_Float16)a3;
    *(f16x4*)(agg + (long)node * 256 + lane * 4) = o;
}

__global__ __launch_bounds__(256) void agg128_f16_kernel(
    const _Float16* __restrict__ x, const int* __restrict__ rowptr,
    const int* __restrict__ csr, _Float16* __restrict__ agg, int n)
{
    int node = (blockIdx.x * 256 + threadIdx.x) >> 5;
    int lane = threadIdx.x & 31;
    if (node >= n) return;
    int beg = rowptr[node], end = rowptr[node + 1];
    float a0 = 0.f, a1 = 0.f, a2 = 0.f, a3 = 0.f;
    for (int j = beg; j < end; ++j) {
        int s = csr[j];
        f16x4 v = *(const f16x4*)(x + (long)s * 128 + lane * 4);
        a0 += (float)v[0]; a1 += (float)v[1]; a2 += (float)v[2]; a3 += (float)v[3];
    }
    f16x4 o; o[0] = (_Float16)a0; o[1] = (_Float16)a1; o[2] = (_Float16)a2; o[3] = (_Float16)a3;
    *(f16x4*)(agg + (long)node * 128 + lane * 4) = o;
}

__global__ __launch_bounds__(256) void agg96_f16_kernel(
    const _Float16* __restrict__ x, const int* __restrict__ rowptr,
    const int* __restrict__ csr, _Float16* __restrict__ agg, int n)
{
    int node = (blockIdx.x * 256 + threadIdx.x) >> 6;
    int lane = threadIdx.x & 63;
    if (node >= n) return;
    if (lane < 48) {
        int beg = rowptr[node], end = rowptr[node + 1];
        float a0 = 0.f, a1 = 0.f;
        for (int j = beg; j < end; ++j) {
            int s = csr[j];
            f16x2 v = *(const f16x2*)(x + (long)s * 96 + lane * 2);
            a0 += (float)v[0]; a1 += (float)v[1];
        }
        f16x2 o; o[0] = (_Float16)a0; o[1] = (_Float16)a1;
        *(f16x2*)(agg + (long)node * 96 + lane * 2) = o;
    }
}

// ---------------------------------------------------------------------------
// pooling (fp16 input, f32 output)
// ---------------------------------------------------------------------------
__global__ __launch_bounds__(256) void pool_comp_kernel(
    const _Float16* __restrict__ x, float* __restrict__ out)
{
    int g = blockIdx.x;
    int c = blockIdx.y * 256 + threadIdx.x;
    float m = -INFINITY;
    for (int r = 0; r < 40; ++r)
        m = fmaxf(m, (float)x[(long)(g * 40 + r) * 512 + c]);
    out[g * 512 + c] = m;
}

#define PSPLIT 4
__global__ __launch_bounds__(256) void pool_prot_partial_kernel(
    const _Float16* __restrict__ x, float* __restrict__ part)
{
    int g = blockIdx.x, cb = blockIdx.y, s = blockIdx.z;
    int col = cb * 256 + threadIdx.x;
    int start = 512 * ((g + 1) / 2) + 1024 * (g / 2);
    int len = (g & 1) ? 1024 : 512;
    int chunk = len / PSPLIT;
    int r0 = s * chunk;
    float m = -INFINITY;
    #pragma unroll 4
    for (int r = 0; r < chunk; ++r)
        m = fmaxf(m, (float)x[(long)(start + r0 + r) * 512 + col]);
    part[(long)(g * PSPLIT + s) * 512 + col] = m;
}

__global__ __launch_bounds__(256) void pool_prot_final_kernel(
    const float* __restrict__ part, float* __restrict__ out)
{
    int g = blockIdx.x;
    int col = blockIdx.y * 256 + threadIdx.x;
    float m = -INFINITY;
    #pragma unroll
    for (int s = 0; s < PSPLIT; ++s)
        m = fmaxf(m, part[(long)(g * PSPLIT + s) * 512 + col]);
    out[g * 512 + col] = m;
}

// ---------------------------------------------------------------------------
// head: cfc/pfc -> concat -> fc1 -> out   (one block per graph, f32)
// ---------------------------------------------------------------------------
__global__ __launch_bounds__(256) void head_kernel(
    const float* __restrict__ cpool, const float* __restrict__ ppool,
    const float* __restrict__ cfc_w, const float* __restrict__ cfc_b,
    const float* __restrict__ pfc_w, const float* __restrict__ pfc_b,
    const float* __restrict__ fc1_w, const float* __restrict__ fc1_b,
    const float* __restrict__ out_w, const float* __restrict__ out_b,
    float* __restrict__ out)
{
    __shared__ float cp[512], pp[512], cf[128], pf[128], h[256], red[256];
    int g = blockIdx.x, t = threadIdx.x;
    for (int i = t; i < 512; i += 256) {
        cp[i] = cpool[g * 512 + i];
        pp[i] = ppool[g * 512 + i];
    }
    __syncthreads();
    if (t < 128) {
        float a = cfc_b[t];
        for (int k = 0; k < 512; k++) a += cp[k] * cfc_w[k * 128 + t];
        cf[t] = lrelu(a);
    } else {
        int o = t - 128;
        float a = pfc_b[o];
        for (int k = 0; k < 512; k++) a += pp[k] * pfc_w[k * 128 + o];
        pf[o] = lrelu(a);
    }
    __syncthreads();
    {
        float a = fc1_b[t];
        for (int k = 0; k < 128; k++) a += cf[k] * fc1_w[k * 256 + t];
        for (int k = 0; k < 128; k++) a += pf[k] * fc1_w[(128 + k) * 256 + t];
        h[t] = lrelu(a);
    }
    __syncthreads();
    red[t] = h[t] * out_w[t];
    __syncthreads();
    for (int s = 128; s > 0; s >>= 1) {
        if (t < s) red[t] += red[t + s];
        __syncthreads();
    }
    if (t == 0) out[g] = red[0] + out_b[0];
}

// ---------------------------------------------------------------------------
// launch
// ---------------------------------------------------------------------------
extern "C" void kernel_launch(void* const* d_in, const int* in_sizes, int n_in,
                              void* d_out, int out_size, void* d_ws, size_t ws_size,
                              hipStream_t stream) {
    const float* seq_x      = (const float*)d_in[0];
    const float* compound_x = (const float*)d_in[1];
    const float* conv_w     = (const float*)d_in[2];
    const float* conv_b     = (const float*)d_in[3];
    const float* c1_wl = (const float*)d_in[4];
    const float* c1_bl = (const float*)d_in[5];
    const float* c1_wr = (const float*)d_in[6];
    const float* c2_wl = (const float*)d_in[7];
    const float* c2_bl = (const float*)d_in[8];
    const float* c2_wr = (const float*)d_in[9];
    const float* c3_wl = (const float*)d_in[10];
    const float* c3_bl = (const float*)d_in[11];
    const float* c3_wr = (const float*)d_in[12];
    const float* cfc_w = (const float*)d_in[13];
    const float* cfc_b = (const float*)d_in[14];
    const float* p1_wl = (const float*)d_in[15];
    const float* p1_bl = (const float*)d_in[16];
    const float* p1_wr = (const float*)d_in[17];
    const float* p2_wl = (const float*)d_in[18];
    const float* p2_bl = (const float*)d_in[19];
    const float* p2_wr = (const float*)d_in[20];
    const float* p3_wl = (const float*)d_in[21];
    const float* p3_bl = (const float*)d_in[22];
    const float* p3_wr = (const float*)d_in[23];
    const float* pfc_w = (const float*)d_in[24];
    const float* pfc_b = (const float*)d_in[25];
    const float* fc1_w = (const float*)d_in[26];
    const float* fc1_b = (const float*)d_in[27];
    const float* out_w = (const float*)d_in[28];
    const float* out_b = (const float*)d_in[29];
    const int* prot_gather = (const int*)d_in[30];
    const int* prot_src    = (const int*)d_in[31];
    const int* prot_tgt    = (const int*)d_in[32];
    const int* comp_src    = (const int*)d_in[33];
    const int* comp_tgt    = (const int*)d_in[34];

    float* out = (float*)d_out;

    // workspace layout
    size_t off = 0;
    auto alloc = [&](size_t bytes) -> char* {
        char* p = (char*)d_ws + off;
        off = (off + bytes + 255) & ~(size_t)255;
        return p;
    };
    // fp16 activation buffers
    _Float16* pim   = (_Float16*)alloc((size_t)NP_TOT * 128 * 2);   // im2col
    _Float16* pconv = (_Float16*)alloc((size_t)NP_TOT * 128 * 2);
    _Float16* pagg  = (_Float16*)alloc((size_t)NP_TOT * 256 * 2);
    _Float16* pl1   = (_Float16*)alloc((size_t)NP_TOT * 128 * 2);
    _Float16* pl2   = (_Float16*)alloc((size_t)NP_TOT * 256 * 2);
    _Float16* pl3   = (_Float16*)alloc((size_t)NP_TOT * 512 * 2);
    _Float16* cxp   = (_Float16*)alloc((size_t)NC_TOT * 96 * 2);
    _Float16* cagg  = (_Float16*)alloc((size_t)NC_TOT * 256 * 2);
    _Float16* cl1   = (_Float16*)alloc((size_t)NC_TOT * 128 * 2);
    _Float16* cl2   = (_Float16*)alloc((size_t)NC_TOT * 256 * 2);
    _Float16* cl3   = (_Float16*)alloc((size_t)NC_TOT * 512 * 2);
    // fp16 transposed weights [D][Kp]
    _Float16* wt_p1l = (_Float16*)alloc(128 * 128 * 2);
    _Float16* wt_p1r = (_Float16*)alloc(128 * 128 * 2);
    _Float16* wt_p2l = (_Float16*)alloc(256 * 128 * 2);
    _Float16* wt_p2r = (_Float16*)alloc(256 * 128 * 2);
    _Float16* wt_p3l = (_Float16*)alloc(512 * 256 * 2);
    _Float16* wt_p3r = (_Float16*)alloc(512 * 256 * 2);
    _Float16* wt_c1l = (_Float16*)alloc(128 * 96 * 2);
    _Float16* wt_c1r = (_Float16*)alloc(128 * 96 * 2);
    _Float16* wt_c2l = (_Float16*)alloc(256 * 128 * 2);
    _Float16* wt_c2r = (_Float16*)alloc(256 * 128 * 2);
    _Float16* wt_c3l = (_Float16*)alloc(512 * 256 * 2);
    _Float16* wt_c3r = (_Float16*)alloc(512 * 256 * 2);
    _Float16* wt_cv  = (_Float16*)alloc(128 * 128 * 2);
    // pools (f32)
    float* cpool = (float*)alloc(B_GRAPHS * 512 * 4);
    float* ppool = (float*)alloc(B_GRAPHS * 512 * 4);
    float* ppart = (float*)alloc((size_t)B_GRAPHS * PSPLIT * 512 * 4);
    // CSR (cursors contiguous so one zero pass covers both)
    int* cursors  = (int*)alloc((NP_TOT + NC_TOT) * 4);
    int* p_cursor = cursors;
    int* c_cursor = cursors + NP_TOT;
    int* p_rowptr = (int*)alloc((NP_TOT + 1) * 4);
    int* p_csr    = (int*)alloc(EP_TOT * 4);
    int* c_rowptr = (int*)alloc((NC_TOT + 1) * 4);
    int* c_csr    = (int*)alloc(EC_TOT * 4);
    int* bsums    = (int*)alloc(SCAN_NB * 4);
    (void)ws_size; (void)n_in; (void)in_sizes; (void)out_size;

    // ---- weight prep (one launch) + compound input conversion ----
    WJobs jobs;
    jobs.j[0]  = { p1_wl, wt_p1l, 128, 128, 128, 0 };
    jobs.j[1]  = { p1_wr, wt_p1r, 128, 128, 128, 0 };
    jobs.j[2]  = { p2_wl, wt_p2l, 128, 256, 128, 0 };
    jobs.j[3]  = { p2_wr, wt_p2r, 128, 256, 128, 0 };
    jobs.j[4]  = { p3_wl, wt_p3l, 256, 512, 256, 0 };
    jobs.j[5]  = { p3_wr, wt_p3r, 256, 512, 256, 0 };
    jobs.j[6]  = { c1_wl, wt_c1l,  78, 128,  96, 0 };
    jobs.j[7]  = { c1_wr, wt_c1r,  78, 128,  96, 0 };
    jobs.j[8]  = { c2_wl, wt_c2l, 128, 256, 128, 0 };
    jobs.j[9]  = { c2_wr, wt_c2r, 128, 256, 128, 0 };
    jobs.j[10] = { c3_wl, wt_c3l, 256, 512, 256, 0 };
    jobs.j[11] = { c3_wr, wt_c3r, 256, 512, 256, 0 };
    jobs.j[12] = { conv_w, wt_cv, 105, 128, 128, 1 };
    wprep_all_kernel<<<dim3(512, 1, 13), 256, 0, stream>>>(jobs);
    cx_conv_kernel<<<(NC_TOT * 96 + 255) / 256, 256, 0, stream>>>(compound_x, cxp);

    // ---- CSR build (both graphs, fused; parallel scan) ----
    zero_int_kernel<<<(SCAN_N + 255) / 256, 256, 0, stream>>>(cursors, SCAN_N);
    hist2_kernel<<<(EP_TOT + EC_TOT + 255) / 256, 256, 0, stream>>>(prot_tgt, p_cursor, comp_tgt, c_cursor);
    scan_bsum_kernel<<<SCAN_NB, 256, 0, stream>>>(cursors, bsums);
    scan_sums_kernel<<<1, 128, 0, stream>>>(bsums);
    scan_final_kernel<<<SCAN_NB, 256, 0, stream>>>(cursors, bsums, p_rowptr, c_rowptr);
    zero_int_kernel<<<(SCAN_N + 255) / 256, 256, 0, stream>>>(cursors, SCAN_N);
    scatter2_kernel<<<(EP_TOT + EC_TOT + 255) / 256, 256, 0, stream>>>(
        prot_src, prot_tgt, p_rowptr, p_cursor, p_csr,
        comp_src, comp_tgt, c_rowptr, c_cursor, c_csr);

    // ---- conv as im2col + MFMA GEMM -> pconv [NP,128] f16 (no activation) ----
    im2col_kernel<<<(NP_TOT * 32 + 255) / 256, 256, 0, stream>>>(seq_x, prot_gather, pim);
    gemm_f16_kernel<<<dim3(NP_TOT / 128, 1), 256, 0, stream>>>(
        pim, wt_cv, pim, wt_cv, conv_b, pconv, NP_TOT, 128, 128, 1, 0);

    // ---- compound GNN ----
    agg96_f16_kernel<<<(NC_TOT + 3) / 4, 256, 0, stream>>>(cxp, c_rowptr, c_csr, cagg, NC_TOT);
    gemm_f16_kernel<<<dim3(NC_TOT / 128, 1), 256, 0, stream>>>(
        cagg, wt_c1l, cxp, wt_c1r, c1_bl, cl1, NC_TOT, 96, 128, 2, 1);
    agg128_f16_kernel<<<(NC_TOT + 7) / 8, 256, 0, stream>>>(cl1, c_rowptr, c_csr, cagg, NC_TOT);
    gemm_f16_kernel<<<dim3(NC_TOT / 128, 2), 256, 0, stream>>>(
        cagg, wt_c2l, cl1, wt_c2r, c2_bl, cl2, NC_TOT, 128, 256, 2, 1);
    agg256_f16_kernel<<<(NC_TOT + 3) / 4, 256, 0, stream>>>(cl2, c_rowptr, c_csr, cagg, NC_TOT);
    gemm_f16_kernel<<<dim3(NC_TOT / 128, 4), 256, 0, stream>>>(
        cagg, wt_c3l, cl2, wt_c3r, c3_bl, cl3, NC_TOT, 256, 512, 2, 1);
    pool_comp_kernel<<<dim3(B_GRAPHS, 2), 256, 0, stream>>>(cl3, cpool);

    // ---- protein GNN ----
    agg128_f16_kernel<<<(NP_TOT + 7) / 8, 256, 0, stream>>>(pconv, p_rowptr, p_csr, pagg, NP_TOT);
    gemm_f16_kernel<<<dim3(NP_TOT / 128, 1), 256, 0, stream>>>(
        pagg, wt_p1l, pconv, wt_p1r, p1_bl, pl1, NP_TOT, 128, 128, 2, 1);
    agg128_f16_kernel<<<(NP_TOT + 7) / 8, 256, 0, stream>>>(pl1, p_rowptr, p_csr, pagg, NP_TOT);
    gemm_f16_kernel<<<dim3(NP_TOT / 128, 2), 256, 0, stream>>>(
        pagg, wt_p2l, pl1, wt_p2r, p2_bl, pl2, NP_TOT, 128, 256, 2, 1);
    agg256_f16_kernel<<<(NP_TOT + 3) / 4, 256, 0, stream>>>(pl2, p_rowptr, p_csr, pagg, NP_TOT);
    gemm_f16_kernel<<<dim3(NP_TOT / 128, 4), 256, 0, stream>>>(
        pagg, wt_p3l, pl2, wt_p3r, p3_bl, pl3, NP_TOT, 256, 512, 2, 1);
    pool_prot_partial_kernel<<<dim3(B_GRAPHS, 2, PSPLIT), 256, 0, stream>>>(pl3, ppart);
    pool_prot_final_kernel<<<dim3(B_GRAPHS, 2), 256, 0, stream>>>(ppart, ppool);

    // ---- head ----
    head_kernel<<<B_GRAPHS, 256, 0, stream>>>(cpool, ppool, cfc_w, cfc_b, pfc_w, pfc_b,
                                              fc1_w, fc1_b, out_w, out_b, out);
}

// Round 7
// 428.319 us; speedup vs baseline: 4.6656x; 1.1310x over previous
//
#include <hip/hip_runtime.h>
#include <hip/hip_fp16.h>

// ---------------------------------------------------------------------------
// Problem constants (from reference)
// ---------------------------------------------------------------------------
#define B_GRAPHS 64
#define LMAX 1024
#define NP_TOT 49152      // sum(LENS)
#define NC_TOT 2560       // 64*40
#define EP_TOT 393216     // 8 * NP
#define EC_TOT 10240      // 4 * NC

#define SCAN_N   (NP_TOT + NC_TOT)   // 51712
#define SCAN_BLK 512
#define SCAN_NB  (SCAN_N / SCAN_BLK) // 101 (exact)

typedef _Float16 f16x8 __attribute__((ext_vector_type(8)));
typedef _Float16 f16x4 __attribute__((ext_vector_type(4)));
typedef _Float16 f16x2 __attribute__((ext_vector_type(2)));
typedef float    f32x4 __attribute__((ext_vector_type(4)));

__device__ __forceinline__ float lrelu(float x) { return x > 0.f ? x : 0.01f * x; }

// ---------------------------------------------------------------------------
// CSR build (fused, both graphs)
// ---------------------------------------------------------------------------
__global__ void zero_int_kernel(int* p, int n) {
    int i = blockIdx.x * blockDim.x + threadIdx.x;
    if (i < n) p[i] = 0;
}

__global__ void hist2_kernel(const int* __restrict__ ptgt, int* __restrict__ pdeg,
                             const int* __restrict__ ctgt, int* __restrict__ cdeg) {
    int e = blockIdx.x * blockDim.x + threadIdx.x;
    if (e < EP_TOT) atomicAdd(&pdeg[ptgt[e]], 1);
    else if (e < EP_TOT + EC_TOT) atomicAdd(&cdeg[ctgt[e - EP_TOT]], 1);
}

// ---- parallel exclusive scan over the concatenated degree array ----
__global__ __launch_bounds__(256) void scan_bsum_kernel(
    const int* __restrict__ deg, int* __restrict__ bsums)
{
    __shared__ int red[256];
    int b = blockIdx.x, t = threadIdx.x;
    int2 e = *(const int2*)(deg + b * SCAN_BLK + t * 2);
    red[t] = e.x + e.y;
    __syncthreads();
    for (int s = 128; s > 0; s >>= 1) {
        if (t < s) red[t] += red[t + s];
        __syncthreads();
    }
    if (t == 0) bsums[b] = red[0];
}

__global__ __launch_bounds__(128) void scan_sums_kernel(int* __restrict__ bsums)
{
    __shared__ int v[SCAN_NB];
    int t = threadIdx.x;
    if (t < SCAN_NB) v[t] = bsums[t];
    __syncthreads();
    if (t == 0) {
        int run = 0;
        for (int i = 0; i < SCAN_NB; ++i) { int x = v[i]; v[i] = run; run += x; }
    }
    __syncthreads();
    if (t < SCAN_NB) bsums[t] = v[t];
}

__global__ __launch_bounds__(256) void scan_final_kernel(
    const int* __restrict__ deg, const int* __restrict__ bsums,
    int* __restrict__ p_rowptr, int* __restrict__ c_rowptr)
{
    __shared__ int wsum[4];
    int b = blockIdx.x, t = threadIdx.x;
    int i = b * SCAN_BLK + t * 2;
    int2 e = *(const int2*)(deg + i);
    int ts = e.x + e.y;
    int lane = t & 63, wv = t >> 6;
    int x = ts;
    #pragma unroll
    for (int o = 1; o < 64; o <<= 1) {
        int y = __shfl_up(x, o);
        if (lane >= o) x += y;
    }
    if (lane == 63) wsum[wv] = x;
    __syncthreads();
    int base = bsums[b];
    for (int w = 0; w < wv; ++w) base += wsum[w];
    int excl = base + x - ts;
    int v0 = excl, v1 = excl + e.x;
    if (i < NP_TOT) p_rowptr[i] = v0; else c_rowptr[i - NP_TOT] = v0 - EP_TOT;
    if (i + 1 < NP_TOT) p_rowptr[i + 1] = v1; else c_rowptr[i + 1 - NP_TOT] = v1 - EP_TOT;
    if (b == 0 && t == 0) { p_rowptr[NP_TOT] = EP_TOT; c_rowptr[NC_TOT] = EC_TOT; }
}

__global__ void scatter2_kernel(const int* __restrict__ ps, const int* __restrict__ pt,
                                const int* __restrict__ prow, int* __restrict__ pcur,
                                int* __restrict__ pcsr,
                                const int* __restrict__ cs, const int* __restrict__ ct,
                                const int* __restrict__ crow, int* __restrict__ ccur,
                                int* __restrict__ ccsr) {
    int e = blockIdx.x * blockDim.x + threadIdx.x;
    if (e < EP_TOT) {
        int t = pt[e];
        int pos = atomicAdd(&pcur[t], 1);
        pcsr[prow[t] + pos] = ps[e];
    } else if (e < EP_TOT + EC_TOT) {
        int e2 = e - EP_TOT;
        int t = ct[e2];
        int pos = atomicAdd(&ccur[t], 1);
        ccsr[crow[t] + pos] = cs[e2];
    }
}

// ---------------------------------------------------------------------------
// fused weight prep: 13 jobs in one launch (blockIdx.z selects)
// ---------------------------------------------------------------------------
struct WJob { const float* in; _Float16* out; int K, D, Kp, mode; };
struct WJobs { WJob j[13]; };

__global__ __launch_bounds__(256) void wprep_all_kernel(WJobs jobs) {
    WJob jb = jobs.j[blockIdx.z];
    int idx = blockIdx.x * 256 + threadIdx.x;
    int total = jb.D * jb.Kp;
    if (idx >= total) return;
    float v;
    if (jb.mode == 0) {
        int d = idx / jb.Kp, k = idx - d * jb.Kp;
        v = (k < jb.K) ? jb.in[(long)k * jb.D + d] : 0.f;
    } else {
        int o = idx >> 7, j = idx & 127;
        if (j < 105) {
            int k = j / 21, c = j - k * 21;
            v = jb.in[o * 105 + c * 5 + k];
        } else v = 0.f;
    }
    jb.out[idx] = (_Float16)v;
}

// compound_x f32 [2560][78] -> f16 [2560][96] zero-padded
__global__ void cx_conv_kernel(const float* __restrict__ in, _Float16* __restrict__ out) {
    int i = blockIdx.x * 256 + threadIdx.x;
    if (i >= NC_TOT * 96) return;
    int r = i / 96, k = i - r * 96;
    out[i] = (_Float16)(k < 78 ? in[r * 78 + k] : 0.f);
}

// ---------------------------------------------------------------------------
// im2col for conv1d(k=5, pad=2, Cin=21): row i -> [128] f16, j = k*21+c
// ---------------------------------------------------------------------------
__global__ __launch_bounds__(256) void im2col_kernel(
    const float* __restrict__ seq, const int* __restrict__ gather,
    _Float16* __restrict__ out)
{
    int t4 = blockIdx.x * 256 + threadIdx.x;   // one f16x4 group
    int i = t4 >> 5;                           // 32 groups per row
    if (i >= NP_TOT) return;
    int j0 = (t4 & 31) * 4;
    int g = gather[i];
    int bb = g >> 10, l = g & (LMAX - 1);
    f16x4 o;
    #pragma unroll
    for (int u = 0; u < 4; ++u) {
        int j = j0 + u;
        float v = 0.f;
        if (j < 105) {
            int k = j / 21, c = j - k * 21;
            int ll = l + k - 2;
            if ((unsigned)ll < (unsigned)LMAX)
                v = seq[((long)bb * LMAX + ll) * 21 + c];
        }
        o[u] = (_Float16)v;
    }
    *(f16x4*)(out + (long)i * 128 + j0) = o;
}

// ---------------------------------------------------------------------------
// fused dual MFMA GEMM (fp16 in, f32 accum, fp16 out)
// ---------------------------------------------------------------------------
__global__ __launch_bounds__(256) void gemm_f16_kernel(
    const _Float16* __restrict__ A0, const _Float16* __restrict__ WT0,
    const _Float16* __restrict__ A1, const _Float16* __restrict__ WT1,
    const float* __restrict__ bias, _Float16* __restrict__ Out,
    int N, int K, int D, int npass, int act)
{
    __shared__ _Float16 Asm[128 * 32];
    __shared__ _Float16 Bsm[128 * 32];
    const int tid = threadIdx.x;
    const int wave = tid >> 6, lane = tid & 63;
    const int wr = wave >> 1, wc = wave & 1;
    const int l15 = lane & 15, lk = lane >> 4;
    const long r0 = (long)blockIdx.x * 128;
    const long c0 = (long)blockIdx.y * 128;

    const int srow = tid >> 2, sc = tid & 3;
    const int w0 = srow * 32 + ((sc ^ (srow & 3)) * 8);
    const int w1 = w0 + 64 * 32;

    int aoff[4], boff[4];
    #pragma unroll
    for (int m = 0; m < 4; ++m) {
        int row = wr * 64 + m * 16 + l15;
        aoff[m] = row * 32 + ((lk ^ (row & 3)) * 8);
        int col = wc * 64 + m * 16 + l15;
        boff[m] = col * 32 + ((lk ^ (col & 3)) * 8);
    }

    f32x4 acc[4][4];
    #pragma unroll
    for (int m = 0; m < 4; ++m)
        #pragma unroll
        for (int n = 0; n < 4; ++n)
            #pragma unroll
            for (int i = 0; i < 4; ++i) acc[m][n][i] = 0.f;

    const int ksteps = K >> 5;
    const int S = ksteps * npass;

    f16x8 av0, av1, bv0, bv1;
    {
        const long kb = sc * 8;
        av0 = *(const f16x8*)(A0  + (r0 + srow) * K + kb);
        av1 = *(const f16x8*)(A0  + (r0 + srow + 64) * K + kb);
        bv0 = *(const f16x8*)(WT0 + (c0 + srow) * K + kb);
        bv1 = *(const f16x8*)(WT0 + (c0 + srow + 64) * K + kb);
    }

    for (int s = 0; s < S; ++s) {
        __syncthreads();
        *(f16x8*)(Asm + w0) = av0;
        *(f16x8*)(Asm + w1) = av1;
        *(f16x8*)(Bsm + w0) = bv0;
        *(f16x8*)(Bsm + w1) = bv1;
        __syncthreads();
        if (s + 1 < S) {
            int s1 = s + 1;
            int pass = (s1 >= ksteps) ? 1 : 0;
            long kb = (long)(s1 - pass * ksteps) * 32 + sc * 8;
            const _Float16* Ax = pass ? A1 : A0;
            const _Float16* Wx = pass ? WT1 : WT0;
            av0 = *(const f16x8*)(Ax + (r0 + srow) * K + kb);
            av1 = *(const f16x8*)(Ax + (r0 + srow + 64) * K + kb);
            bv0 = *(const f16x8*)(Wx + (c0 + srow) * K + kb);
            bv1 = *(const f16x8*)(Wx + (c0 + srow + 64) * K + kb);
        }
        f16x8 af[4], bf[4];
        #pragma unroll
        for (int m = 0; m < 4; ++m) af[m] = *(const f16x8*)(Asm + aoff[m]);
        #pragma unroll
        for (int n = 0; n < 4; ++n) bf[n] = *(const f16x8*)(Bsm + boff[n]);
        #pragma unroll
        for (int m = 0; m < 4; ++m)
            #pragma unroll
            for (int n = 0; n < 4; ++n)
                acc[m][n] = __builtin_amdgcn_mfma_f32_16x16x32_f16(af[m], bf[n], acc[m][n], 0, 0, 0);
    }

    float bn[4]; int coln[4];
    #pragma unroll
    for (int n = 0; n < 4; ++n) {
        coln[n] = (int)c0 + wc * 64 + n * 16 + l15;
        bn[n] = bias[coln[n]];
    }
    #pragma unroll
    for (int m = 0; m < 4; ++m) {
        long rowb = r0 + wr * 64 + m * 16 + lk * 4;
        #pragma unroll
        for (int i = 0; i < 4; ++i) {
            long row = rowb + i;
            #pragma unroll
            for (int n = 0; n < 4; ++n) {
                float v = acc[m][n][i] + bn[n];
                if (act) v = v > 0.f ? v : 0.01f * v;
                Out[row * D + coln[n]] = (_Float16)v;
            }
        }
    }
}

// ---------------------------------------------------------------------------
// CSR aggregation, latency-optimized: f16x8 lanes + chunk-of-4 index prefetch.
// D/8 lanes per node; indices loaded in batches of 4 (clamped tail), then 4
// independent 16B gathers, then predicated f32 accumulation in j-order.
// ---------------------------------------------------------------------------
template<int D>
__global__ __launch_bounds__(256) void agg_f16x8_kernel(
    const _Float16* __restrict__ x, const int* __restrict__ rowptr,
    const int* __restrict__ csr, _Float16* __restrict__ agg, int n)
{
    constexpr int LPN = D / 8;                 // 32 (D=256) or 16 (D=128)
    int node = (blockIdx.x * 256 + threadIdx.x) / LPN;
    int lane = threadIdx.x & (LPN - 1);
    if (node >= n) return;
    int beg = rowptr[node], end = rowptr[node + 1];
    float acc[8] = {};
    const long lo = lane * 8;
    for (int j = beg; j < end; j += 4) {
        int r = end - j;
        int s0 = csr[j];
        int s1 = (r > 1) ? csr[j + 1] : s0;
        int s2 = (r > 2) ? csr[j + 2] : s0;
        int s3 = (r > 3) ? csr[j + 3] : s0;
        f16x8 v0 = *(const f16x8*)(x + (long)s0 * D + lo);
        f16x8 v1 = *(const f16x8*)(x + (long)s1 * D + lo);
        f16x8 v2 = *(const f16x8*)(x + (long)s2 * D + lo);
        f16x8 v3 = *(const f16x8*)(x + (long)s3 * D + lo);
        #pragma unroll
        for (int u = 0; u < 8; ++u) acc[u] += (float)v0[u];
        if (r > 1) {
            #pragma unroll
            for (int u = 0; u < 8; ++u) acc[u] += (float)v1[u];
        }
        if (r > 2) {
            #pragma unroll
            for (int u = 0; u < 8; ++u) acc[u] += (float)v2[u];
        }
        if (r > 3) {
            #pragma unroll
            for (int u = 0; u < 8; ++u) acc[u] += (float)v3[u];
        }
    }
    f16x8 o;
    #pragma unroll
    for (int u = 0; u < 8; ++u) o[u] = (_Float16)acc[u];
    *(f16x8*)(agg + (long)node * D + lo) = o;
}

__global__ __launch_bounds__(256) void agg96_f16_kernel(
    const _Float16* __restrict__ x, const int* __restrict__ rowptr,
    const int* __restrict__ csr, _Float16* __restrict__ agg, int n)
{
    int node = (blockIdx.x * 256 + threadIdx.x) >> 6;
    int lane = threadIdx.x & 63;
    if (node >= n) return;
    if (lane < 48) {
        int beg = rowptr[node], end = rowptr[node + 1];
        float a0 = 0.f, a1 = 0.f;
        for (int j = beg; j < end; ++j) {
            int s = csr[j];
            f16x2 v = *(const f16x2*)(x + (long)s * 96 + lane * 2);
            a0 += (float)v[0]; a1 += (float)v[1];
        }
        f16x2 o; o[0] = (_Float16)a0; o[1] = (_Float16)a1;
        *(f16x2*)(agg + (long)node * 96 + lane * 2) = o;
    }
}

// ---------------------------------------------------------------------------
// pooling (fp16 input, f32 output)
// ---------------------------------------------------------------------------
__global__ __launch_bounds__(256) void pool_comp_kernel(
    const _Float16* __restrict__ x, float* __restrict__ out)
{
    int g = blockIdx.x;
    int c = blockIdx.y * 256 + threadIdx.x;
    float m = -INFINITY;
    for (int r = 0; r < 40; ++r)
        m = fmaxf(m, (float)x[(long)(g * 40 + r) * 512 + c]);
    out[g * 512 + c] = m;
}

#define PSPLIT 4
__global__ __launch_bounds__(256) void pool_prot_partial_kernel(
    const _Float16* __restrict__ x, float* __restrict__ part)
{
    int g = blockIdx.x, cb = blockIdx.y, s = blockIdx.z;
    int col = cb * 256 + threadIdx.x;
    int start = 512 * ((g + 1) / 2) + 1024 * (g / 2);
    int len = (g & 1) ? 1024 : 512;
    int chunk = len / PSPLIT;
    int r0 = s * chunk;
    float m = -INFINITY;
    #pragma unroll 4
    for (int r = 0; r < chunk; ++r)
        m = fmaxf(m, (float)x[(long)(start + r0 + r) * 512 + col]);
    part[(long)(g * PSPLIT + s) * 512 + col] = m;
}

__global__ __launch_bounds__(256) void pool_prot_final_kernel(
    const float* __restrict__ part, float* __restrict__ out)
{
    int g = blockIdx.x;
    int col = blockIdx.y * 256 + threadIdx.x;
    float m = -INFINITY;
    #pragma unroll
    for (int s = 0; s < PSPLIT; ++s)
        m = fmaxf(m, part[(long)(g * PSPLIT + s) * 512 + col]);
    out[g * 512 + col] = m;
}

// ---------------------------------------------------------------------------
// head: cfc/pfc -> concat -> fc1 -> out   (one block per graph, f32)
// ---------------------------------------------------------------------------
__global__ __launch_bounds__(256) void head_kernel(
    const float* __restrict__ cpool, const float* __restrict__ ppool,
    const float* __restrict__ cfc_w, const float* __restrict__ cfc_b,
    const float* __restrict__ pfc_w, const float* __restrict__ pfc_b,
    const float* __restrict__ fc1_w, const float* __restrict__ fc1_b,
    const float* __restrict__ out_w, const float* __restrict__ out_b,
    float* __restrict__ out)
{
    __shared__ float cp[512], pp[512], cf[128], pf[128], h[256], red[256];
    int g = blockIdx.x, t = threadIdx.x;
    for (int i = t; i < 512; i += 256) {
        cp[i] = cpool[g * 512 + i];
        pp[i] = ppool[g * 512 + i];
    }
    __syncthreads();
    if (t < 128) {
        float a = cfc_b[t];
        for (int k = 0; k < 512; k++) a += cp[k] * cfc_w[k * 128 + t];
        cf[t] = lrelu(a);
    } else {
        int o = t - 128;
        float a = pfc_b[o];
        for (int k = 0; k < 512; k++) a += pp[k] * pfc_w[k * 128 + o];
        pf[o] = lrelu(a);
    }
    __syncthreads();
    {
        float a = fc1_b[t];
        for (int k = 0; k < 128; k++) a += cf[k] * fc1_w[k * 256 + t];
        for (int k = 0; k < 128; k++) a += pf[k] * fc1_w[(128 + k) * 256 + t];
        h[t] = lrelu(a);
    }
    __syncthreads();
    red[t] = h[t] * out_w[t];
    __syncthreads();
    for (int s = 128; s > 0; s >>= 1) {
        if (t < s) red[t] += red[t + s];
        __syncthreads();
    }
    if (t == 0) out[g] = red[0] + out_b[0];
}

// ---------------------------------------------------------------------------
// launch
// ---------------------------------------------------------------------------
extern "C" void kernel_launch(void* const* d_in, const int* in_sizes, int n_in,
                              void* d_out, int out_size, void* d_ws, size_t ws_size,
                              hipStream_t stream) {
    const float* seq_x      = (const float*)d_in[0];
    const float* compound_x = (const float*)d_in[1];
    const float* conv_w     = (const float*)d_in[2];
    const float* conv_b     = (const float*)d_in[3];
    const float* c1_wl = (const float*)d_in[4];
    const float* c1_bl = (const float*)d_in[5];
    const float* c1_wr = (const float*)d_in[6];
    const float* c2_wl = (const float*)d_in[7];
    const float* c2_bl = (const float*)d_in[8];
    const float* c2_wr = (const float*)d_in[9];
    const float* c3_wl = (const float*)d_in[10];
    const float* c3_bl = (const float*)d_in[11];
    const float* c3_wr = (const float*)d_in[12];
    const float* cfc_w = (const float*)d_in[13];
    const float* cfc_b = (const float*)d_in[14];
    const float* p1_wl = (const float*)d_in[15];
    const float* p1_bl = (const float*)d_in[16];
    const float* p1_wr = (const float*)d_in[17];
    const float* p2_wl = (const float*)d_in[18];
    const float* p2_bl = (const float*)d_in[19];
    const float* p2_wr = (const float*)d_in[20];
    const float* p3_wl = (const float*)d_in[21];
    const float* p3_bl = (const float*)d_in[22];
    const float* p3_wr = (const float*)d_in[23];
    const float* pfc_w = (const float*)d_in[24];
    const float* pfc_b = (const float*)d_in[25];
    const float* fc1_w = (const float*)d_in[26];
    const float* fc1_b = (const float*)d_in[27];
    const float* out_w = (const float*)d_in[28];
    const float* out_b = (const float*)d_in[29];
    const int* prot_gather = (const int*)d_in[30];
    const int* prot_src    = (const int*)d_in[31];
    const int* prot_tgt    = (const int*)d_in[32];
    const int* comp_src    = (const int*)d_in[33];
    const int* comp_tgt    = (const int*)d_in[34];

    float* out = (float*)d_out;

    // workspace layout
    size_t off = 0;
    auto alloc = [&](size_t bytes) -> char* {
        char* p = (char*)d_ws + off;
        off = (off + bytes + 255) & ~(size_t)255;
        return p;
    };
    // fp16 activation buffers
    _Float16* pim   = (_Float16*)alloc((size_t)NP_TOT * 128 * 2);   // im2col
    _Float16* pconv = (_Float16*)alloc((size_t)NP_TOT * 128 * 2);
    _Float16* pagg  = (_Float16*)alloc((size_t)NP_TOT * 256 * 2);
    _Float16* pl1   = (_Float16*)alloc((size_t)NP_TOT * 128 * 2);
    _Float16* pl2   = (_Float16*)alloc((size_t)NP_TOT * 256 * 2);
    _Float16* pl3   = (_Float16*)alloc((size_t)NP_TOT * 512 * 2);
    _Float16* cxp   = (_Float16*)alloc((size_t)NC_TOT * 96 * 2);
    _Float16* cagg  = (_Float16*)alloc((size_t)NC_TOT * 256 * 2);
    _Float16* cl1   = (_Float16*)alloc((size_t)NC_TOT * 128 * 2);
    _Float16* cl2   = (_Float16*)alloc((size_t)NC_TOT * 256 * 2);
    _Float16* cl3   = (_Float16*)alloc((size_t)NC_TOT * 512 * 2);
    // fp16 transposed weights [D][Kp]
    _Float16* wt_p1l = (_Float16*)alloc(128 * 128 * 2);
    _Float16* wt_p1r = (_Float16*)alloc(128 * 128 * 2);
    _Float16* wt_p2l = (_Float16*)alloc(256 * 128 * 2);
    _Float16* wt_p2r = (_Float16*)alloc(256 * 128 * 2);
    _Float16* wt_p3l = (_Float16*)alloc(512 * 256 * 2);
    _Float16* wt_p3r = (_Float16*)alloc(512 * 256 * 2);
    _Float16* wt_c1l = (_Float16*)alloc(128 * 96 * 2);
    _Float16* wt_c1r = (_Float16*)alloc(128 * 96 * 2);
    _Float16* wt_c2l = (_Float16*)alloc(256 * 128 * 2);
    _Float16* wt_c2r = (_Float16*)alloc(256 * 128 * 2);
    _Float16* wt_c3l = (_Float16*)alloc(512 * 256 * 2);
    _Float16* wt_c3r = (_Float16*)alloc(512 * 256 * 2);
    _Float16* wt_cv  = (_Float16*)alloc(128 * 128 * 2);
    // pools (f32)
    float* cpool = (float*)alloc(B_GRAPHS * 512 * 4);
    float* ppool = (float*)alloc(B_GRAPHS * 512 * 4);
    float* ppart = (float*)alloc((size_t)B_GRAPHS * PSPLIT * 512 * 4);
    // CSR (cursors contiguous so one zero pass covers both)
    int* cursors  = (int*)alloc((NP_TOT + NC_TOT) * 4);
    int* p_cursor = cursors;
    int* c_cursor = cursors + NP_TOT;
    int* p_rowptr = (int*)alloc((NP_TOT + 1) * 4);
    int* p_csr    = (int*)alloc(EP_TOT * 4);
    int* c_rowptr = (int*)alloc((NC_TOT + 1) * 4);
    int* c_csr    = (int*)alloc(EC_TOT * 4);
    int* bsums    = (int*)alloc(SCAN_NB * 4);
    (void)ws_size; (void)n_in; (void)in_sizes; (void)out_size;

    // ---- weight prep (one launch) + compound input conversion ----
    WJobs jobs;
    jobs.j[0]  = { p1_wl, wt_p1l, 128, 128, 128, 0 };
    jobs.j[1]  = { p1_wr, wt_p1r, 128, 128, 128, 0 };
    jobs.j[2]  = { p2_wl, wt_p2l, 128, 256, 128, 0 };
    jobs.j[3]  = { p2_wr, wt_p2r, 128, 256, 128, 0 };
    jobs.j[4]  = { p3_wl, wt_p3l, 256, 512, 256, 0 };
    jobs.j[5]  = { p3_wr, wt_p3r, 256, 512, 256, 0 };
    jobs.j[6]  = { c1_wl, wt_c1l,  78, 128,  96, 0 };
    jobs.j[7]  = { c1_wr, wt_c1r,  78, 128,  96, 0 };
    jobs.j[8]  = { c2_wl, wt_c2l, 128, 256, 128, 0 };
    jobs.j[9]  = { c2_wr, wt_c2r, 128, 256, 128, 0 };
    jobs.j[10] = { c3_wl, wt_c3l, 256, 512, 256, 0 };
    jobs.j[11] = { c3_wr, wt_c3r, 256, 512, 256, 0 };
    jobs.j[12] = { conv_w, wt_cv, 105, 128, 128, 1 };
    wprep_all_kernel<<<dim3(512, 1, 13), 256, 0, stream>>>(jobs);
    cx_conv_kernel<<<(NC_TOT * 96 + 255) / 256, 256, 0, stream>>>(compound_x, cxp);

    // ---- CSR build (both graphs, fused; parallel scan) ----
    zero_int_kernel<<<(SCAN_N + 255) / 256, 256, 0, stream>>>(cursors, SCAN_N);
    hist2_kernel<<<(EP_TOT + EC_TOT + 255) / 256, 256, 0, stream>>>(prot_tgt, p_cursor, comp_tgt, c_cursor);
    scan_bsum_kernel<<<SCAN_NB, 256, 0, stream>>>(cursors, bsums);
    scan_sums_kernel<<<1, 128, 0, stream>>>(bsums);
    scan_final_kernel<<<SCAN_NB, 256, 0, stream>>>(cursors, bsums, p_rowptr, c_rowptr);
    zero_int_kernel<<<(SCAN_N + 255) / 256, 256, 0, stream>>>(cursors, SCAN_N);
    scatter2_kernel<<<(EP_TOT + EC_TOT + 255) / 256, 256, 0, stream>>>(
        prot_src, prot_tgt, p_rowptr, p_cursor, p_csr,
        comp_src, comp_tgt, c_rowptr, c_cursor, c_csr);

    // ---- conv as im2col + MFMA GEMM -> pconv [NP,128] f16 (no activation) ----
    im2col_kernel<<<(NP_TOT * 32 + 255) / 256, 256, 0, stream>>>(seq_x, prot_gather, pim);
    gemm_f16_kernel<<<dim3(NP_TOT / 128, 1), 256, 0, stream>>>(
        pim, wt_cv, pim, wt_cv, conv_b, pconv, NP_TOT, 128, 128, 1, 0);

    // ---- compound GNN ----
    agg96_f16_kernel<<<(NC_TOT + 3) / 4, 256, 0, stream>>>(cxp, c_rowptr, c_csr, cagg, NC_TOT);
    gemm_f16_kernel<<<dim3(NC_TOT / 128, 1), 256, 0, stream>>>(
        cagg, wt_c1l, cxp, wt_c1r, c1_bl, cl1, NC_TOT, 96, 128, 2, 1);
    agg_f16x8_kernel<128><<<(NC_TOT * 16 + 255) / 256, 256, 0, stream>>>(cl1, c_rowptr, c_csr, cagg, NC_TOT);
    gemm_f16_kernel<<<dim3(NC_TOT / 128, 2), 256, 0, stream>>>(
        cagg, wt_c2l, cl1, wt_c2r, c2_bl, cl2, NC_TOT, 128, 256, 2, 1);
    agg_f16x8_kernel<256><<<(NC_TOT * 32 + 255) / 256, 256, 0, stream>>>(cl2, c_rowptr, c_csr, cagg, NC_TOT);
    gemm_f16_kernel<<<dim3(NC_TOT / 128, 4), 256, 0, stream>>>(
        cagg, wt_c3l, cl2, wt_c3r, c3_bl, cl3, NC_TOT, 256, 512, 2, 1);
    pool_comp_kernel<<<dim3(B_GRAPHS, 2), 256, 0, stream>>>(cl3, cpool);

    // ---- protein GNN ----
    agg_f16x8_kernel<128><<<(NP_TOT * 16 + 255) / 256, 256, 0, stream>>>(pconv, p_rowptr, p_csr, pagg, NP_TOT);
    gemm_f16_kernel<<<dim3(NP_TOT / 128, 1), 256, 0, stream>>>(
        pagg, wt_p1l, pconv, wt_p1r, p1_bl, pl1, NP_TOT, 128, 128, 2, 1);
    agg_f16x8_kernel<128><<<(NP_TOT * 16 + 255) / 256, 256, 0, stream>>>(pl1, p_rowptr, p_csr, pagg, NP_TOT);
    gemm_f16_kernel<<<dim3(NP_TOT / 128, 2), 256, 0, stream>>>(
        pagg, wt_p2l, pl1, wt_p2r, p2_bl, pl2, NP_TOT, 128, 256, 2, 1);
    agg_f16x8_kernel<256><<<(NP_TOT * 32 + 255) / 256, 256, 0, stream>>>(pl2, p_rowptr, p_csr, pagg, NP_TOT);
    gemm_f16_kernel<<<dim3(NP_TOT / 128, 4), 256, 0, stream>>>(
        pagg, wt_p3l, pl2, wt_p3r, p3_bl, pl3, NP_TOT, 256, 512, 2, 1);
    pool_prot_partial_kernel<<<dim3(B_GRAPHS, 2, PSPLIT), 256, 0, stream>>>(pl3, ppart);
    pool_prot_final_kernel<<<dim3(B_GRAPHS, 2), 256, 0, stream>>>(ppart, ppool);

    // ---- head ----
    head_kernel<<<B_GRAPHS, 256, 0, stream>>>(cpool, ppool, cfc_w, cfc_b, pfc_w, pfc_b,
                                              fc1_w, fc1_b, out_w, out_b, out);
}

// Round 9
// 399.394 us; speedup vs baseline: 5.0035x; 1.0724x over previous
//
#include <hip/hip_runtime.h>
#include <hip/hip_fp16.h>

// ---------------------------------------------------------------------------
// Problem constants (from reference)
// ---------------------------------------------------------------------------
#define B_GRAPHS 64
#define LMAX 1024
#define NP_TOT 49152      // sum(LENS)
#define NC_TOT 2560       // 64*40
#define EP_TOT 393216     // 8 * NP
#define EC_TOT 10240      // 4 * NC

#define SCAN_N   (NP_TOT + NC_TOT)   // 51712
#define SCAN_BLK 512
#define SCAN_NB  (SCAN_N / SCAN_BLK) // 101 (exact)

typedef _Float16 f16x8 __attribute__((ext_vector_type(8)));
typedef _Float16 f16x4 __attribute__((ext_vector_type(4)));
typedef _Float16 f16x2 __attribute__((ext_vector_type(2)));
typedef float    f32x4 __attribute__((ext_vector_type(4)));

__device__ __forceinline__ float lrelu(float x) { return x > 0.f ? x : 0.01f * x; }

// ---------------------------------------------------------------------------
// CSR build (fused, both graphs)
// ---------------------------------------------------------------------------
__global__ void zero_int_kernel(int* p, int n) {
    int i = blockIdx.x * blockDim.x + threadIdx.x;
    if (i < n) p[i] = 0;
}

__global__ void hist2_kernel(const int* __restrict__ ptgt, int* __restrict__ pdeg,
                             const int* __restrict__ ctgt, int* __restrict__ cdeg) {
    int e = blockIdx.x * blockDim.x + threadIdx.x;
    if (e < EP_TOT) atomicAdd(&pdeg[ptgt[e]], 1);
    else if (e < EP_TOT + EC_TOT) atomicAdd(&cdeg[ctgt[e - EP_TOT]], 1);
}

// ---- parallel exclusive scan over the concatenated degree array ----
__global__ __launch_bounds__(256) void scan_bsum_kernel(
    const int* __restrict__ deg, int* __restrict__ bsums)
{
    __shared__ int red[256];
    int b = blockIdx.x, t = threadIdx.x;
    int2 e = *(const int2*)(deg + b * SCAN_BLK + t * 2);
    red[t] = e.x + e.y;
    __syncthreads();
    for (int s = 128; s > 0; s >>= 1) {
        if (t < s) red[t] += red[t + s];
        __syncthreads();
    }
    if (t == 0) bsums[b] = red[0];
}

__global__ __launch_bounds__(128) void scan_sums_kernel(int* __restrict__ bsums)
{
    __shared__ int v[SCAN_NB];
    int t = threadIdx.x;
    if (t < SCAN_NB) v[t] = bsums[t];
    __syncthreads();
    if (t == 0) {
        int run = 0;
        for (int i = 0; i < SCAN_NB; ++i) { int x = v[i]; v[i] = run; run += x; }
    }
    __syncthreads();
    if (t < SCAN_NB) bsums[t] = v[t];
}

__global__ __launch_bounds__(256) void scan_final_kernel(
    const int* __restrict__ deg, const int* __restrict__ bsums,
    int* __restrict__ p_rowptr, int* __restrict__ c_rowptr)
{
    __shared__ int wsum[4];
    int b = blockIdx.x, t = threadIdx.x;
    int i = b * SCAN_BLK + t * 2;
    int2 e = *(const int2*)(deg + i);
    int ts = e.x + e.y;
    int lane = t & 63, wv = t >> 6;
    int x = ts;
    #pragma unroll
    for (int o = 1; o < 64; o <<= 1) {
        int y = __shfl_up(x, o);
        if (lane >= o) x += y;
    }
    if (lane == 63) wsum[wv] = x;
    __syncthreads();
    int base = bsums[b];
    for (int w = 0; w < wv; ++w) base += wsum[w];
    int excl = base + x - ts;
    int v0 = excl, v1 = excl + e.x;
    if (i < NP_TOT) p_rowptr[i] = v0; else c_rowptr[i - NP_TOT] = v0 - EP_TOT;
    if (i + 1 < NP_TOT) p_rowptr[i + 1] = v1; else c_rowptr[i + 1 - NP_TOT] = v1 - EP_TOT;
    if (b == 0 && t == 0) { p_rowptr[NP_TOT] = EP_TOT; c_rowptr[NC_TOT] = EC_TOT; }
}

__global__ void scatter2_kernel(const int* __restrict__ ps, const int* __restrict__ pt,
                                const int* __restrict__ prow, int* __restrict__ pcur,
                                int* __restrict__ pcsr,
                                const int* __restrict__ cs, const int* __restrict__ ct,
                                const int* __restrict__ crow, int* __restrict__ ccur,
                                int* __restrict__ ccsr) {
    int e = blockIdx.x * blockDim.x + threadIdx.x;
    if (e < EP_TOT) {
        int t = pt[e];
        int pos = atomicAdd(&pcur[t], 1);
        pcsr[prow[t] + pos] = ps[e];
    } else if (e < EP_TOT + EC_TOT) {
        int e2 = e - EP_TOT;
        int t = ct[e2];
        int pos = atomicAdd(&ccur[t], 1);
        ccsr[crow[t] + pos] = cs[e2];
    }
}

// ---------------------------------------------------------------------------
// fused weight prep: 13 jobs in one launch (blockIdx.z selects)
// ---------------------------------------------------------------------------
struct WJob { const float* in; _Float16* out; int K, D, Kp, mode; };
struct WJobs { WJob j[13]; };

__global__ __launch_bounds__(256) void wprep_all_kernel(WJobs jobs) {
    WJob jb = jobs.j[blockIdx.z];
    int idx = blockIdx.x * 256 + threadIdx.x;
    int total = jb.D * jb.Kp;
    if (idx >= total) return;
    float v;
    if (jb.mode == 0) {
        int d = idx / jb.Kp, k = idx - d * jb.Kp;
        v = (k < jb.K) ? jb.in[(long)k * jb.D + d] : 0.f;
    } else {
        int o = idx >> 7, j = idx & 127;
        if (j < 105) {
            int k = j / 21, c = j - k * 21;
            v = jb.in[o * 105 + c * 5 + k];
        } else v = 0.f;
    }
    jb.out[idx] = (_Float16)v;
}

// compound_x f32 [2560][78] -> f16 [2560][96] zero-padded
__global__ void cx_conv_kernel(const float* __restrict__ in, _Float16* __restrict__ out) {
    int i = blockIdx.x * 256 + threadIdx.x;
    if (i >= NC_TOT * 96) return;
    int r = i / 96, k = i - r * 96;
    out[i] = (_Float16)(k < 78 ? in[r * 78 + k] : 0.f);
}

// ---------------------------------------------------------------------------
// im2col for conv1d(k=5, pad=2, Cin=21): row i -> [128] f16, j = k*21+c
// ---------------------------------------------------------------------------
__global__ __launch_bounds__(256) void im2col_kernel(
    const float* __restrict__ seq, const int* __restrict__ gather,
    _Float16* __restrict__ out)
{
    int t4 = blockIdx.x * 256 + threadIdx.x;   // one f16x4 group
    int i = t4 >> 5;                           // 32 groups per row
    if (i >= NP_TOT) return;
    int j0 = (t4 & 31) * 4;
    int g = gather[i];
    int bb = g >> 10, l = g & (LMAX - 1);
    f16x4 o;
    #pragma unroll
    for (int u = 0; u < 4; ++u) {
        int j = j0 + u;
        float v = 0.f;
        if (j < 105) {
            int k = j / 21, c = j - k * 21;
            int ll = l + k - 2;
            if ((unsigned)ll < (unsigned)LMAX)
                v = seq[((long)bb * LMAX + ll) * 21 + c];
        }
        o[u] = (_Float16)v;
    }
    *(f16x4*)(out + (long)i * 128 + j0) = o;
}

// ---------------------------------------------------------------------------
// fused dual MFMA GEMM (fp16 in, f32 accum, fp16 out)
// ---------------------------------------------------------------------------
__global__ __launch_bounds__(256) void gemm_f16_kernel(
    const _Float16* __restrict__ A0, const _Float16* __restrict__ WT0,
    const _Float16* __restrict__ A1, const _Float16* __restrict__ WT1,
    const float* __restrict__ bias, _Float16* __restrict__ Out,
    int N, int K, int D, int npass, int act)
{
    __shared__ _Float16 Asm[128 * 32];
    __shared__ _Float16 Bsm[128 * 32];
    const int tid = threadIdx.x;
    const int wave = tid >> 6, lane = tid & 63;
    const int wr = wave >> 1, wc = wave & 1;
    const int l15 = lane & 15, lk = lane >> 4;
    const long r0 = (long)blockIdx.x * 128;
    const long c0 = (long)blockIdx.y * 128;

    const int srow = tid >> 2, sc = tid & 3;
    const int w0 = srow * 32 + ((sc ^ (srow & 3)) * 8);
    const int w1 = w0 + 64 * 32;

    int aoff[4], boff[4];
    #pragma unroll
    for (int m = 0; m < 4; ++m) {
        int row = wr * 64 + m * 16 + l15;
        aoff[m] = row * 32 + ((lk ^ (row & 3)) * 8);
        int col = wc * 64 + m * 16 + l15;
        boff[m] = col * 32 + ((lk ^ (col & 3)) * 8);
    }

    f32x4 acc[4][4];
    #pragma unroll
    for (int m = 0; m < 4; ++m)
        #pragma unroll
        for (int n = 0; n < 4; ++n)
            #pragma unroll
            for (int i = 0; i < 4; ++i) acc[m][n][i] = 0.f;

    const int ksteps = K >> 5;
    const int S = ksteps * npass;

    f16x8 av0, av1, bv0, bv1;
    {
        const long kb = sc * 8;
        av0 = *(const f16x8*)(A0  + (r0 + srow) * K + kb);
        av1 = *(const f16x8*)(A0  + (r0 + srow + 64) * K + kb);
        bv0 = *(const f16x8*)(WT0 + (c0 + srow) * K + kb);
        bv1 = *(const f16x8*)(WT0 + (c0 + srow + 64) * K + kb);
    }

    for (int s = 0; s < S; ++s) {
        __syncthreads();
        *(f16x8*)(Asm + w0) = av0;
        *(f16x8*)(Asm + w1) = av1;
        *(f16x8*)(Bsm + w0) = bv0;
        *(f16x8*)(Bsm + w1) = bv1;
        __syncthreads();
        if (s + 1 < S) {
            int s1 = s + 1;
            int pass = (s1 >= ksteps) ? 1 : 0;
            long kb = (long)(s1 - pass * ksteps) * 32 + sc * 8;
            const _Float16* Ax = pass ? A1 : A0;
            const _Float16* Wx = pass ? WT1 : WT0;
            av0 = *(const f16x8*)(Ax + (r0 + srow) * K + kb);
            av1 = *(const f16x8*)(Ax + (r0 + srow + 64) * K + kb);
            bv0 = *(const f16x8*)(Wx + (c0 + srow) * K + kb);
            bv1 = *(const f16x8*)(Wx + (c0 + srow + 64) * K + kb);
        }
        f16x8 af[4], bf[4];
        #pragma unroll
        for (int m = 0; m < 4; ++m) af[m] = *(const f16x8*)(Asm + aoff[m]);
        #pragma unroll
        for (int n = 0; n < 4; ++n) bf[n] = *(const f16x8*)(Bsm + boff[n]);
        #pragma unroll
        for (int m = 0; m < 4; ++m)
            #pragma unroll
            for (int n = 0; n < 4; ++n)
                acc[m][n] = __builtin_amdgcn_mfma_f32_16x16x32_f16(af[m], bf[n], acc[m][n], 0, 0, 0);
    }

    float bn[4]; int coln[4];
    #pragma unroll
    for (int n = 0; n < 4; ++n) {
        coln[n] = (int)c0 + wc * 64 + n * 16 + l15;
        bn[n] = bias[coln[n]];
    }
    #pragma unroll
    for (int m = 0; m < 4; ++m) {
        long rowb = r0 + wr * 64 + m * 16 + lk * 4;
        #pragma unroll
        for (int i = 0; i < 4; ++i) {
            long row = rowb + i;
            #pragma unroll
            for (int n = 0; n < 4; ++n) {
                float v = acc[m][n][i] + bn[n];
                if (act) v = v > 0.f ? v : 0.01f * v;
                Out[row * D + coln[n]] = (_Float16)v;
            }
        }
    }
}

// ---------------------------------------------------------------------------
// CSR aggregation, latency-optimized: f16x8 lanes + chunk-of-4 index prefetch.
// ---------------------------------------------------------------------------
template<int D>
__global__ __launch_bounds__(256) void agg_f16x8_kernel(
    const _Float16* __restrict__ x, const int* __restrict__ rowptr,
    const int* __restrict__ csr, _Float16* __restrict__ agg, int n)
{
    constexpr int LPN = D / 8;                 // 32 (D=256) or 16 (D=128)
    int node = (blockIdx.x * 256 + threadIdx.x) / LPN;
    int lane = threadIdx.x & (LPN - 1);
    if (node >= n) return;
    int beg = rowptr[node], end = rowptr[node + 1];
    float acc[8] = {};
    const long lo = lane * 8;
    for (int j = beg; j < end; j += 4) {
        int r = end - j;
        int s0 = csr[j];
        int s1 = (r > 1) ? csr[j + 1] : s0;
        int s2 = (r > 2) ? csr[j + 2] : s0;
        int s3 = (r > 3) ? csr[j + 3] : s0;
        f16x8 v0 = *(const f16x8*)(x + (long)s0 * D + lo);
        f16x8 v1 = *(const f16x8*)(x + (long)s1 * D + lo);
        f16x8 v2 = *(const f16x8*)(x + (long)s2 * D + lo);
        f16x8 v3 = *(const f16x8*)(x + (long)s3 * D + lo);
        #pragma unroll
        for (int u = 0; u < 8; ++u) acc[u] += (float)v0[u];
        if (r > 1) {
            #pragma unroll
            for (int u = 0; u < 8; ++u) acc[u] += (float)v1[u];
        }
        if (r > 2) {
            #pragma unroll
            for (int u = 0; u < 8; ++u) acc[u] += (float)v2[u];
        }
        if (r > 3) {
            #pragma unroll
            for (int u = 0; u < 8; ++u) acc[u] += (float)v3[u];
        }
    }
    f16x8 o;
    #pragma unroll
    for (int u = 0; u < 8; ++u) o[u] = (_Float16)acc[u];
    *(f16x8*)(agg + (long)node * D + lo) = o;
}

__global__ __launch_bounds__(256) void agg96_f16_kernel(
    const _Float16* __restrict__ x, const int* __restrict__ rowptr,
    const int* __restrict__ csr, _Float16* __restrict__ agg, int n)
{
    int node = (blockIdx.x * 256 + threadIdx.x) >> 6;
    int lane = threadIdx.x & 63;
    if (node >= n) return;
    if (lane < 48) {
        int beg = rowptr[node], end = rowptr[node + 1];
        float a0 = 0.f, a1 = 0.f;
        for (int j = beg; j < end; ++j) {
            int s = csr[j];
            f16x2 v = *(const f16x2*)(x + (long)s * 96 + lane * 2);
            a0 += (float)v[0]; a1 += (float)v[1];
        }
        f16x2 o; o[0] = (_Float16)a0; o[1] = (_Float16)a1;
        *(f16x2*)(agg + (long)node * 96 + lane * 2) = o;
    }
}

// ---------------------------------------------------------------------------
// pooling, vectorized f16x8 (16B/lane coalesced)
// ---------------------------------------------------------------------------
// compound: one block per graph; 64 col-groups x 4 row-subgroups; LDS combine
__global__ __launch_bounds__(256) void pool_comp_kernel(
    const _Float16* __restrict__ x, float* __restrict__ out)
{
    __shared__ float sm[4][512];
    int g = blockIdx.x;
    int cg = threadIdx.x & 63, rs = threadIdx.x >> 6;
    float m[8];
    #pragma unroll
    for (int u = 0; u < 8; ++u) m[u] = -INFINITY;
    for (int r = rs; r < 40; r += 4) {
        f16x8 v = *(const f16x8*)(x + (long)(g * 40 + r) * 512 + cg * 8);
        #pragma unroll
        for (int u = 0; u < 8; ++u) m[u] = fmaxf(m[u], (float)v[u]);
    }
    #pragma unroll
    for (int u = 0; u < 8; ++u) sm[rs][cg * 8 + u] = m[u];
    __syncthreads();
    if (rs == 0) {
        #pragma unroll
        for (int u = 0; u < 8; ++u) {
            int c = cg * 8 + u;
            out[g * 512 + c] = fmaxf(fmaxf(sm[0][c], sm[1][c]), fmaxf(sm[2][c], sm[3][c]));
        }
    }
}

// protein partial: grid (64 graphs, PSPLIT row-splits), block = 64 cg x 4 rs
#define PSPLIT 8
#define PPART  (PSPLIT * 4)   // 32 partials per graph
__global__ __launch_bounds__(256) void pool_prot_partial_kernel(
    const _Float16* __restrict__ x, float* __restrict__ part)
{
    int g = blockIdx.x, s = blockIdx.y;
    int cg = threadIdx.x & 63, rs = threadIdx.x >> 6;
    int start = 512 * ((g + 1) / 2) + 1024 * (g / 2);
    int len = (g & 1) ? 1024 : 512;
    int chunk = len / PSPLIT;     // 64 or 128
    int sub = chunk >> 2;         // 16 or 32 rows per thread
    long r0 = start + s * chunk + rs * sub;
    float m[8];
    #pragma unroll
    for (int u = 0; u < 8; ++u) m[u] = -INFINITY;
    for (int r = 0; r < sub; ++r) {
        f16x8 v = *(const f16x8*)(x + (r0 + r) * 512 + cg * 8);
        #pragma unroll
        for (int u = 0; u < 8; ++u) m[u] = fmaxf(m[u], (float)v[u]);
    }
    float* o = part + (long)((g * PSPLIT + s) * 4 + rs) * 512 + cg * 8;
    #pragma unroll
    for (int u = 0; u < 8; ++u) o[u] = m[u];
}

__global__ __launch_bounds__(256) void pool_prot_final_kernel(
    const float* __restrict__ part, float* __restrict__ out)
{
    int g = blockIdx.x;
    int col = blockIdx.y * 256 + threadIdx.x;
    float m = -INFINITY;
    #pragma unroll 8
    for (int p = 0; p < PPART; ++p)
        m = fmaxf(m, part[(long)(g * PPART + p) * 512 + col]);
    out[g * 512 + col] = m;
}

// ---------------------------------------------------------------------------
// head: cfc/pfc -> concat -> fc1 -> out   (one block per graph, f32)
// ---------------------------------------------------------------------------
__global__ __launch_bounds__(256) void head_kernel(
    const float* __restrict__ cpool, const float* __restrict__ ppool,
    const float* __restrict__ cfc_w, const float* __restrict__ cfc_b,
    const float* __restrict__ pfc_w, const float* __restrict__ pfc_b,
    const float* __restrict__ fc1_w, const float* __restrict__ fc1_b,
    const float* __restrict__ out_w, const float* __restrict__ out_b,
    float* __restrict__ out)
{
    __shared__ float cp[512], pp[512], cf[128], pf[128], h[256], red[256];
    int g = blockIdx.x, t = threadIdx.x;
    for (int i = t; i < 512; i += 256) {
        cp[i] = cpool[g * 512 + i];
        pp[i] = ppool[g * 512 + i];
    }
    __syncthreads();
    if (t < 128) {
        float a = cfc_b[t];
        for (int k = 0; k < 512; k++) a += cp[k] * cfc_w[k * 128 + t];
        cf[t] = lrelu(a);
    } else {
        int o = t - 128;
        float a = pfc_b[o];
        for (int k = 0; k < 512; k++) a += pp[k] * pfc_w[k * 128 + o];
        pf[o] = lrelu(a);
    }
    __syncthreads();
    {
        float a = fc1_b[t];
        for (int k = 0; k < 128; k++) a += cf[k] * fc1_w[k * 256 + t];
        for (int k = 0; k < 128; k++) a += pf[k] * fc1_w[(128 + k) * 256 + t];
        h[t] = lrelu(a);
    }
    __syncthreads();
    red[t] = h[t] * out_w[t];
    __syncthreads();
    for (int s = 128; s > 0; s >>= 1) {
        if (t < s) red[t] += red[t + s];
        __syncthreads();
    }
    if (t == 0) out[g] = red[0] + out_b[0];
}

// ---------------------------------------------------------------------------
// launch
// ---------------------------------------------------------------------------
extern "C" void kernel_launch(void* const* d_in, const int* in_sizes, int n_in,
                              void* d_out, int out_size, void* d_ws, size_t ws_size,
                              hipStream_t stream) {
    const float* seq_x      = (const float*)d_in[0];
    const float* compound_x = (const float*)d_in[1];
    const float* conv_w     = (const float*)d_in[2];
    const float* conv_b     = (const float*)d_in[3];
    const float* c1_wl = (const float*)d_in[4];
    const float* c1_bl = (const float*)d_in[5];
    const float* c1_wr = (const float*)d_in[6];
    const float* c2_wl = (const float*)d_in[7];
    const float* c2_bl = (const float*)d_in[8];
    const float* c2_wr = (const float*)d_in[9];
    const float* c3_wl = (const float*)d_in[10];
    const float* c3_bl = (const float*)d_in[11];
    const float* c3_wr = (const float*)d_in[12];
    const float* cfc_w = (const float*)d_in[13];
    const float* cfc_b = (const float*)d_in[14];
    const float* p1_wl = (const float*)d_in[15];
    const float* p1_bl = (const float*)d_in[16];
    const float* p1_wr = (const float*)d_in[17];
    const float* p2_wl = (const float*)d_in[18];
    const float* p2_bl = (const float*)d_in[19];
    const float* p2_wr = (const float*)d_in[20];
    const float* p3_wl = (const float*)d_in[21];
    const float* p3_bl = (const float*)d_in[22];
    const float* p3_wr = (const float*)d_in[23];
    const float* pfc_w = (const float*)d_in[24];
    const float* pfc_b = (const float*)d_in[25];
    const float* fc1_w = (const float*)d_in[26];
    const float* fc1_b = (const float*)d_in[27];
    const float* out_w = (const float*)d_in[28];
    const float* out_b = (const float*)d_in[29];
    const int* prot_gather = (const int*)d_in[30];
    const int* prot_src    = (const int*)d_in[31];
    const int* prot_tgt    = (const int*)d_in[32];
    const int* comp_src    = (const int*)d_in[33];
    const int* comp_tgt    = (const int*)d_in[34];

    float* out = (float*)d_out;

    // workspace layout
    size_t off = 0;
    auto alloc = [&](size_t bytes) -> char* {
        char* p = (char*)d_ws + off;
        off = (off + bytes + 255) & ~(size_t)255;
        return p;
    };
    // fp16 activation buffers
    _Float16* pim   = (_Float16*)alloc((size_t)NP_TOT * 128 * 2);   // im2col
    _Float16* pconv = (_Float16*)alloc((size_t)NP_TOT * 128 * 2);
    _Float16* pagg  = (_Float16*)alloc((size_t)NP_TOT * 256 * 2);
    _Float16* pl1   = (_Float16*)alloc((size_t)NP_TOT * 128 * 2);
    _Float16* pl2   = (_Float16*)alloc((size_t)NP_TOT * 256 * 2);
    _Float16* pl3   = (_Float16*)alloc((size_t)NP_TOT * 512 * 2);
    _Float16* cxp   = (_Float16*)alloc((size_t)NC_TOT * 96 * 2);
    _Float16* cagg  = (_Float16*)alloc((size_t)NC_TOT * 256 * 2);
    _Float16* cl1   = (_Float16*)alloc((size_t)NC_TOT * 128 * 2);
    _Float16* cl2   = (_Float16*)alloc((size_t)NC_TOT * 256 * 2);
    _Float16* cl3   = (_Float16*)alloc((size_t)NC_TOT * 512 * 2);
    // fp16 transposed weights [D][Kp]
    _Float16* wt_p1l = (_Float16*)alloc(128 * 128 * 2);
    _Float16* wt_p1r = (_Float16*)alloc(128 * 128 * 2);
    _Float16* wt_p2l = (_Float16*)alloc(256 * 128 * 2);
    _Float16* wt_p2r = (_Float16*)alloc(256 * 128 * 2);
    _Float16* wt_p3l = (_Float16*)alloc(512 * 256 * 2);
    _Float16* wt_p3r = (_Float16*)alloc(512 * 256 * 2);
    _Float16* wt_c1l = (_Float16*)alloc(128 * 96 * 2);
    _Float16* wt_c1r = (_Float16*)alloc(128 * 96 * 2);
    _Float16* wt_c2l = (_Float16*)alloc(256 * 128 * 2);
    _Float16* wt_c2r = (_Float16*)alloc(256 * 128 * 2);
    _Float16* wt_c3l = (_Float16*)alloc(512 * 256 * 2);
    _Float16* wt_c3r = (_Float16*)alloc(512 * 256 * 2);
    _Float16* wt_cv  = (_Float16*)alloc(128 * 128 * 2);
    // pools (f32)
    float* cpool = (float*)alloc(B_GRAPHS * 512 * 4);
    float* ppool = (float*)alloc(B_GRAPHS * 512 * 4);
    float* ppart = (float*)alloc((size_t)B_GRAPHS * PPART * 512 * 4);
    // CSR (cursors contiguous so one zero pass covers both)
    int* cursors  = (int*)alloc((NP_TOT + NC_TOT) * 4);
    int* p_cursor = cursors;
    int* c_cursor = cursors + NP_TOT;
    int* p_rowptr = (int*)alloc((NP_TOT + 1) * 4);
    int* p_csr    = (int*)alloc(EP_TOT * 4);
    int* c_rowptr = (int*)alloc((NC_TOT + 1) * 4);
    int* c_csr    = (int*)alloc(EC_TOT * 4);
    int* bsums    = (int*)alloc(SCAN_NB * 4);
    (void)ws_size; (void)n_in; (void)in_sizes; (void)out_size;

    // ---- weight prep (one launch) + compound input conversion ----
    WJobs jobs;
    jobs.j[0]  = { p1_wl, wt_p1l, 128, 128, 128, 0 };
    jobs.j[1]  = { p1_wr, wt_p1r, 128, 128, 128, 0 };
    jobs.j[2]  = { p2_wl, wt_p2l, 128, 256, 128, 0 };
    jobs.j[3]  = { p2_wr, wt_p2r, 128, 256, 128, 0 };
    jobs.j[4]  = { p3_wl, wt_p3l, 256, 512, 256, 0 };
    jobs.j[5]  = { p3_wr, wt_p3r, 256, 512, 256, 0 };
    jobs.j[6]  = { c1_wl, wt_c1l,  78, 128,  96, 0 };
    jobs.j[7]  = { c1_wr, wt_c1r,  78, 128,  96, 0 };
    jobs.j[8]  = { c2_wl, wt_c2l, 128, 256, 128, 0 };
    jobs.j[9]  = { c2_wr, wt_c2r, 128, 256, 128, 0 };
    jobs.j[10] = { c3_wl, wt_c3l, 256, 512, 256, 0 };
    jobs.j[11] = { c3_wr, wt_c3r, 256, 512, 256, 0 };
    jobs.j[12] = { conv_w, wt_cv, 105, 128, 128, 1 };
    wprep_all_kernel<<<dim3(512, 1, 13), 256, 0, stream>>>(jobs);
    cx_conv_kernel<<<(NC_TOT * 96 + 255) / 256, 256, 0, stream>>>(compound_x, cxp);

    // ---- CSR build (both graphs, fused; parallel scan) ----
    zero_int_kernel<<<(SCAN_N + 255) / 256, 256, 0, stream>>>(cursors, SCAN_N);
    hist2_kernel<<<(EP_TOT + EC_TOT + 255) / 256, 256, 0, stream>>>(prot_tgt, p_cursor, comp_tgt, c_cursor);
    scan_bsum_kernel<<<SCAN_NB, 256, 0, stream>>>(cursors, bsums);
    scan_sums_kernel<<<1, 128, 0, stream>>>(bsums);
    scan_final_kernel<<<SCAN_NB, 256, 0, stream>>>(cursors, bsums, p_rowptr, c_rowptr);
    zero_int_kernel<<<(SCAN_N + 255) / 256, 256, 0, stream>>>(cursors, SCAN_N);
    scatter2_kernel<<<(EP_TOT + EC_TOT + 255) / 256, 256, 0, stream>>>(
        prot_src, prot_tgt, p_rowptr, p_cursor, p_csr,
        comp_src, comp_tgt, c_rowptr, c_cursor, c_csr);

    // ---- conv as im2col + MFMA GEMM -> pconv [NP,128] f16 (no activation) ----
    im2col_kernel<<<(NP_TOT * 32 + 255) / 256, 256, 0, stream>>>(seq_x, prot_gather, pim);
    gemm_f16_kernel<<<dim3(NP_TOT / 128, 1), 256, 0, stream>>>(
        pim, wt_cv, pim, wt_cv, conv_b, pconv, NP_TOT, 128, 128, 1, 0);

    // ---- compound GNN ----
    agg96_f16_kernel<<<(NC_TOT + 3) / 4, 256, 0, stream>>>(cxp, c_rowptr, c_csr, cagg, NC_TOT);
    gemm_f16_kernel<<<dim3(NC_TOT / 128, 1), 256, 0, stream>>>(
        cagg, wt_c1l, cxp, wt_c1r, c1_bl, cl1, NC_TOT, 96, 128, 2, 1);
    agg_f16x8_kernel<128><<<(NC_TOT * 16 + 255) / 256, 256, 0, stream>>>(cl1, c_rowptr, c_csr, cagg, NC_TOT);
    gemm_f16_kernel<<<dim3(NC_TOT / 128, 2), 256, 0, stream>>>(
        cagg, wt_c2l, cl1, wt_c2r, c2_bl, cl2, NC_TOT, 128, 256, 2, 1);
    agg_f16x8_kernel<256><<<(NC_TOT * 32 + 255) / 256, 256, 0, stream>>>(cl2, c_rowptr, c_csr, cagg, NC_TOT);
    gemm_f16_kernel<<<dim3(NC_TOT / 128, 4), 256, 0, stream>>>(
        cagg, wt_c3l, cl2, wt_c3r, c3_bl, cl3, NC_TOT, 256, 512, 2, 1);
    pool_comp_kernel<<<B_GRAPHS, 256, 0, stream>>>(cl3, cpool);

    // ---- protein GNN ----
    agg_f16x8_kernel<128><<<(NP_TOT * 16 + 255) / 256, 256, 0, stream>>>(pconv, p_rowptr, p_csr, pagg, NP_TOT);
    gemm_f16_kernel<<<dim3(NP_TOT / 128, 1), 256, 0, stream>>>(
        pagg, wt_p1l, pconv, wt_p1r, p1_bl, pl1, NP_TOT, 128, 128, 2, 1);
    agg_f16x8_kernel<128><<<(NP_TOT * 16 + 255) / 256, 256, 0, stream>>>(pl1, p_rowptr, p_csr, pagg, NP_TOT);
    gemm_f16_kernel<<<dim3(NP_TOT / 128, 2), 256, 0, stream>>>(
        pagg, wt_p2l, pl1, wt_p2r, p2_bl, pl2, NP_TOT, 128, 256, 2, 1);
    agg_f16x8_kernel<256><<<(NP_TOT * 32 + 255) / 256, 256, 0, stream>>>(pl2, p_rowptr, p_csr, pagg, NP_TOT);
    gemm_f16_kernel<<<dim3(NP_TOT / 128, 4), 256, 0, stream>>>(
        pagg, wt_p3l, pl2, wt_p3r, p3_bl, pl3, NP_TOT, 256, 512, 2, 1);
    pool_prot_partial_kernel<<<dim3(B_GRAPHS, PSPLIT), 256, 0, stream>>>(pl3, ppart);
    pool_prot_final_kernel<<<dim3(B_GRAPHS, 2), 256, 0, stream>>>(ppart, ppool);

    // ---- head ----
    head_kernel<<<B_GRAPHS, 256, 0, stream>>>(cpool, ppool, cfc_w, cfc_b, pfc_w, pfc_b,
                                              fc1_w, fc1_b, out_w, out_b, out);
}